// Round 1
// baseline (1040.394 us; speedup 1.0000x reference)
//
#include <hip/hip_runtime.h>
#include <math.h>

typedef _Float16 f16;
typedef f16 f16x8 __attribute__((ext_vector_type(8)));
typedef float f32x4 __attribute__((ext_vector_type(4)));

#define MFMA16(a,b,c) __builtin_amdgcn_mfma_f32_16x16x32_f16(a,b,c,0,0,0)

static __device__ __forceinline__ f16x8 ld8(const f16* p) { return *(const f16x8*)p; }

// ---------------- f32 -> f16 convert (8 elems/thread) ----------------
__global__ __launch_bounds__(256) void k_cvt(const float* __restrict__ in, f16* __restrict__ out) {
    int idx = blockIdx.x * 256 + threadIdx.x;
    int base = idx * 8;
    float4 a = *(const float4*)&in[base];
    float4 b = *(const float4*)&in[base + 4];
    f16x8 v;
    v[0]=(f16)a.x; v[1]=(f16)a.y; v[2]=(f16)a.z; v[3]=(f16)a.w;
    v[4]=(f16)b.x; v[5]=(f16)b.y; v[6]=(f16)b.z; v[7]=(f16)b.w;
    *(f16x8*)&out[base] = v;
}

// ---------------- transpose f32 [K=2048][inCols] -> f16 [inCols][2048] (row offset) ----------------
__global__ __launch_bounds__(256) void k_transpose(const float* __restrict__ in, f16* __restrict__ out,
                                                   int inCols, int rowOff) {
    __shared__ float tile[32][33];
    int tx = threadIdx.x, ty = threadIdx.y;
    int x = blockIdx.x * 32 + tx;
    int y0 = blockIdx.y * 32;
    #pragma unroll
    for (int i = 0; i < 4; ++i)
        tile[ty + i*8][tx] = in[(size_t)(y0 + ty + i*8) * inCols + x];
    __syncthreads();
    #pragma unroll
    for (int i = 0; i < 4; ++i)
        out[(size_t)(rowOff + blockIdx.x*32 + ty + i*8) * 2048 + y0 + tx] = (f16)tile[tx][ty + i*8];
}

// ---------------- gating MLP in f64: logits + iw ----------------
__global__ __launch_bounds__(256) void k_mlp(const float* __restrict__ h, const float* __restrict__ w1,
                                             const float* __restrict__ b1, const float* __restrict__ w2,
                                             const float* __restrict__ b2, double* __restrict__ logitsD,
                                             float* __restrict__ iw) {
    __shared__ float hl[4 * 2048];
    __shared__ double tl[4][64];
    int tid = threadIdx.x;
    int s0 = blockIdx.x * 4;
    #pragma unroll
    for (int p = 0; p < 8; ++p) {
        int off = p * 1024 + tid * 4;
        *(float4*)&hl[off] = *(const float4*)&h[(size_t)s0 * 2048 + off];
    }
    __syncthreads();
    int j = tid & 63, r = tid >> 6;
    const float* hr = &hl[r * 2048];
    double acc = 0.0;
    for (int c = 0; c < 2048; ++c) acc += (double)hr[c] * (double)w1[c * 64 + j];
    acc += (double)b1[j];
    tl[r][j] = tanh(acc);
    __syncthreads();
    int lane = tid & 63, rr = tid >> 6;
    double v = tl[rr][lane] * (double)w2[lane];
    for (int o = 32; o > 0; o >>= 1) v += __shfl_down(v, o);
    if (lane == 0) {
        double lg = v + (double)b2[0] - 1.8562979903656263; // log(4096/640)
        logitsD[s0 + rr] = lg;
        iw[s0 + rr] = (float)(1.0 / (1.0 + exp(-lg)));
    }
}

// ---------------- top-2048 of 4096 via single-block bitonic sort ----------------
__global__ __launch_bounds__(1024) void k_topk(const double* __restrict__ logitsD, int* __restrict__ sel) {
    __shared__ unsigned long long rv[4096];
    __shared__ int ridx[4096];
    int tid = threadIdx.x;
    for (int i = tid; i < 4096; i += 1024) {
        unsigned long long u = (unsigned long long)__double_as_longlong(logitsD[i]);
        u ^= (u >> 63) ? 0xFFFFFFFFFFFFFFFFull : 0x8000000000000000ull; // ascending order map
        rv[i] = ~u;   // ascending sort of rv => descending logit
        ridx[i] = i;
    }
    __syncthreads();
    for (int k = 2; k <= 4096; k <<= 1) {
        for (int jj = k >> 1; jj > 0; jj >>= 1) {
            for (int i = tid; i < 4096; i += 1024) {
                int ij = i ^ jj;
                if (ij > i) {
                    bool up = ((i & k) == 0);
                    unsigned long long a = rv[i], b = rv[ij];
                    bool gt = (a > b) || (a == b && ridx[i] > ridx[ij]);
                    if (gt == up) {
                        rv[i] = b; rv[ij] = a;
                        int t = ridx[i]; ridx[i] = ridx[ij]; ridx[ij] = t;
                    }
                }
            }
            __syncthreads();
        }
    }
    for (int i = tid; i < 2048; i += 1024) sel[i] = ridx[i];
}

// ---------------- f16 GEMM: C[M][N] = A[M][K] * Bt[N][K]^T, f32 out ----------------
__global__ __launch_bounds__(256) void k_gemm(const f16* __restrict__ A, const f16* __restrict__ Bt,
                                              float* __restrict__ C, int M, int N, int K) {
    __shared__ f16 As[128 * 32];
    __shared__ f16 Bs[128 * 32];
    int tid = threadIdx.x;
    int w = tid >> 6, l = tid & 63, lr = l & 15, lg = l >> 4;
    int wr = w >> 1, wc = w & 1;
    int row0 = blockIdx.y * 128, col0 = blockIdx.x * 128;
    f32x4 zero = {0.f, 0.f, 0.f, 0.f};
    f32x4 acc[4][4];
    #pragma unroll
    for (int m = 0; m < 4; ++m)
        #pragma unroll
        for (int n = 0; n < 4; ++n) acc[m][n] = zero;
    for (int k0 = 0; k0 < K; k0 += 32) {
        #pragma unroll
        for (int p = 0; p < 2; ++p) {
            int id = p * 256 + tid;
            int r = id >> 2, c8 = (id & 3) * 8;
            *(int4*)&As[id * 8] = *(const int4*)&A[(size_t)(row0 + r) * K + k0 + c8];
            *(int4*)&Bs[id * 8] = *(const int4*)&Bt[(size_t)(col0 + r) * K + k0 + c8];
        }
        __syncthreads();
        f16x8 a[4], b[4];
        #pragma unroll
        for (int m = 0; m < 4; ++m) a[m] = ld8(&As[(wr*64 + m*16 + lr) * 32 + lg*8]);
        #pragma unroll
        for (int n = 0; n < 4; ++n) b[n] = ld8(&Bs[(wc*64 + n*16 + lr) * 32 + lg*8]);
        #pragma unroll
        for (int m = 0; m < 4; ++m)
            #pragma unroll
            for (int n = 0; n < 4; ++n)
                acc[m][n] = MFMA16(a[m], b[n], acc[m][n]);
        __syncthreads();
    }
    #pragma unroll
    for (int m = 0; m < 4; ++m)
        #pragma unroll
        for (int n = 0; n < 4; ++n)
            #pragma unroll
            for (int i = 0; i < 4; ++i)
                C[(size_t)(row0 + wr*64 + m*16 + lg*4 + i) * N + col0 + wc*64 + n*16 + lr] = acc[m][n][i];
}

// ---------------- q: RMSnorm + RoPE + fold 1/sqrt(128), f16 out ----------------
__global__ __launch_bounds__(256) void k_normq(const float* __restrict__ qkv, const float* __restrict__ qnw,
                                               const float* __restrict__ cosb, const float* __restrict__ sinb,
                                               f16* __restrict__ qr) {
    int s = blockIdx.x;
    int tid = threadIdx.x;
    int h = tid >> 4, ln = tid & 15, d0 = ln * 8;
    const float* src = &qkv[(size_t)s * 3072 + h * 128 + d0];
    float4 a = *(const float4*)src, b = *(const float4*)(src + 4);
    float x[8] = {a.x,a.y,a.z,a.w,b.x,b.y,b.z,b.w};
    float ss = 0;
    #pragma unroll
    for (int j = 0; j < 8; ++j) ss += x[j]*x[j];
    ss += __shfl_xor(ss,1); ss += __shfl_xor(ss,2); ss += __shfl_xor(ss,4); ss += __shfl_xor(ss,8);
    float rn = rsqrtf(ss * (1.0f/128.0f) + 1e-6f);
    float xn[8];
    #pragma unroll
    for (int j = 0; j < 8; ++j) xn[j] = x[j] * rn * qnw[d0 + j];
    const float scl = 0.08838834764831845f; // 1/sqrt(128)
    f16x8 o;
    #pragma unroll
    for (int j = 0; j < 8; ++j) {
        float pr = __shfl_xor(xn[j], 8);      // element at d +/- 64 (same head)
        float rot = (ln < 8) ? -pr : pr;
        int d = d0 + j;
        o[j] = (f16)((xn[j]*cosb[s*128 + d] + rot*sinb[s*128 + d]) * scl);
    }
    *(f16x8*)&qr[(size_t)s * 2048 + h * 128 + d0] = o;
}

// ---------------- k: RMSnorm, f32 out ----------------
__global__ __launch_bounds__(64) void k_normk(const float* __restrict__ qkv, const float* __restrict__ knw,
                                              float* __restrict__ kn) {
    int s = blockIdx.x;
    int tid = threadIdx.x;
    int h = tid >> 4, ln = tid & 15, d0 = ln * 8;
    const float* src = &qkv[(size_t)s * 3072 + 2048 + h * 128 + d0];
    float4 a = *(const float4*)src, b = *(const float4*)(src + 4);
    float x[8] = {a.x,a.y,a.z,a.w,b.x,b.y,b.z,b.w};
    float ss = 0;
    #pragma unroll
    for (int j = 0; j < 8; ++j) ss += x[j]*x[j];
    ss += __shfl_xor(ss,1); ss += __shfl_xor(ss,2); ss += __shfl_xor(ss,4); ss += __shfl_xor(ss,8);
    float rn = rsqrtf(ss * (1.0f/128.0f) + 1e-6f);
    float o[8];
    #pragma unroll
    for (int j = 0; j < 8; ++j) o[j] = x[j] * rn * knw[d0 + j];
    float* dst = &kn[(size_t)s*512 + h*128 + d0];
    *(float4*)dst = make_float4(o[0],o[1],o[2],o[3]);
    *(float4*)(dst+4) = make_float4(o[4],o[5],o[6],o[7]);
}

// ---------------- gather detail keys (rope) + values ----------------
__global__ __launch_bounds__(128) void k_gather(const int* __restrict__ sel, const float* __restrict__ kn,
                                                const float* __restrict__ qkv, const float* __restrict__ cosb,
                                                const float* __restrict__ sinb, f16* __restrict__ Kf,
                                                f16* __restrict__ VfT) {
    int j = blockIdx.x;
    int s = sel[j];
    int t = threadIdx.x; // 0..127
    float c = cosb[s*128 + t], sn = sinb[s*128 + t];
    #pragma unroll
    for (int h = 0; h < 4; ++h) {
        float x  = kn[(size_t)s*512 + h*128 + t];
        float pr = kn[(size_t)s*512 + h*128 + (t ^ 64)];
        float rot = (t < 64) ? -pr : pr;
        Kf[(size_t)(h*2688 + j) * 128 + t] = (f16)(x*c + rot*sn);
        float v = qkv[(size_t)s*3072 + 2560 + h*128 + t];
        VfT[(size_t)h*128*2688 + (size_t)t*2688 + j] = (f16)v;
    }
}

// ---------------- sketch stage 1: T[which][mb][sa][512] = sum_sb kron_b * (k_n|v)*iw ----------------
__global__ __launch_bounds__(256) void k_sketch1(const float* __restrict__ kn, const float* __restrict__ qkv,
                                                 const float* __restrict__ iw, const float* __restrict__ kronb,
                                                 float* __restrict__ T) {
    int mb = blockIdx.x & 31, sa = blockIdx.x >> 5;
    int which = blockIdx.y;
    int c0 = threadIdx.x * 2;
    float a0 = 0, a1 = 0;
    for (int sb = 0; sb < 256; ++sb) {
        int s = sa * 256 + sb;
        float wgt = kronb[mb * 256 + sb] * iw[s];
        const float* src = which ? &qkv[(size_t)s*3072 + 2560] : &kn[(size_t)s*512];
        a0 += wgt * src[c0];
        a1 += wgt * src[c0 + 1];
    }
    float* dst = &T[(size_t)((which*32 + mb)*16 + sa) * 512 + c0];
    dst[0] = a0; dst[1] = a1;
}

// ---------------- sketch stage 2: contract kron_a (sa<16), write sketch keys/values ----------------
__global__ __launch_bounds__(256) void k_sketch2(const float* __restrict__ T, const float* __restrict__ krona,
                                                 const float* __restrict__ sscale, f16* __restrict__ Kf,
                                                 f16* __restrict__ VfT) {
    int m = blockIdx.x;      // 0..639
    int which = blockIdx.y;  // 0=k, 1=v
    int ma = m >> 5, mb = m & 31;
    int c0 = threadIdx.x * 2;
    float sc = sscale[0];
    float a0 = 0, a1 = 0;
    #pragma unroll
    for (int sa = 0; sa < 16; ++sa) {
        float ka = krona[ma * 128 + sa];
        const float* t = &T[(size_t)((which*32 + mb)*16 + sa) * 512 + c0];
        a0 += ka * t[0];
        a1 += ka * t[1];
    }
    a0 *= sc; a1 *= sc;
    int key = 2048 + m;
    int h0 = c0 >> 7, d = c0 & 127;
    if (which == 0) {
        Kf[(size_t)(h0*2688 + key)*128 + d]     = (f16)a0;
        Kf[(size_t)(h0*2688 + key)*128 + d + 1] = (f16)a1;
    } else {
        VfT[(size_t)h0*128*2688 + (size_t)d*2688 + key]       = (f16)a0;
        VfT[(size_t)h0*128*2688 + (size_t)(d+1)*2688 + key]   = (f16)a1;
    }
}

// ---------------- flash attention: 4 waves x 16 q-rows, 2688 keys ----------------
__global__ __launch_bounds__(256) void k_attn(const f16* __restrict__ qr, const f16* __restrict__ Kf,
                                              const f16* __restrict__ VfT, f16* __restrict__ out16) {
    __shared__ f16 P[4][16][32];
    int qt = blockIdx.x, h = blockIdx.y;
    int kvh = h >> 2;
    int tid = threadIdx.x;
    int w = tid >> 6, l = tid & 63, lr = l & 15, lg = l >> 4;
    int q0 = qt * 64 + w * 16;
    const f16* Kb = Kf + (size_t)kvh * 2688 * 128;
    const f16* Vb = VfT + (size_t)kvh * 128 * 2688;
    f16x8 aq[4];
    #pragma unroll
    for (int c = 0; c < 4; ++c)
        aq[c] = ld8(&qr[(size_t)(q0 + lr) * 2048 + h*128 + c*32 + lg*8]);
    f32x4 zero = {0.f,0.f,0.f,0.f};
    f32x4 o[8];
    #pragma unroll
    for (int f = 0; f < 8; ++f) o[f] = zero;
    float m[4] = {-1e30f,-1e30f,-1e30f,-1e30f};
    float ls[4] = {0.f,0.f,0.f,0.f};
    for (int kt = 0; kt < 2688; kt += 32) {
        f32x4 s0 = zero, s1 = zero;
        #pragma unroll
        for (int c = 0; c < 4; ++c) {
            f16x8 b0 = ld8(&Kb[(size_t)(kt + lr) * 128 + c*32 + lg*8]);
            s0 = MFMA16(aq[c], b0, s0);
        }
        #pragma unroll
        for (int c = 0; c < 4; ++c) {
            f16x8 b1 = ld8(&Kb[(size_t)(kt + 16 + lr) * 128 + c*32 + lg*8]);
            s1 = MFMA16(aq[c], b1, s1);
        }
        float cf[4];
        #pragma unroll
        for (int i = 0; i < 4; ++i) {
            float rm = fmaxf(s0[i], s1[i]);
            rm = fmaxf(rm, __shfl_xor(rm, 1));
            rm = fmaxf(rm, __shfl_xor(rm, 2));
            rm = fmaxf(rm, __shfl_xor(rm, 4));
            rm = fmaxf(rm, __shfl_xor(rm, 8));
            float mn = fmaxf(m[i], rm);
            cf[i] = expf(m[i] - mn);
            m[i] = mn;
            float p0 = expf(s0[i] - mn);
            float p1 = expf(s1[i] - mn);
            s0[i] = p0; s1[i] = p1;
            float rs = p0 + p1;
            rs += __shfl_xor(rs, 1);
            rs += __shfl_xor(rs, 2);
            rs += __shfl_xor(rs, 4);
            rs += __shfl_xor(rs, 8);
            ls[i] = ls[i] * cf[i] + rs;
        }
        f32x4 cfv = {cf[0], cf[1], cf[2], cf[3]};
        #pragma unroll
        for (int f = 0; f < 8; ++f) o[f] *= cfv;
        #pragma unroll
        for (int i = 0; i < 4; ++i) {
            P[w][lg*4 + i][lr]      = (f16)s0[i];
            P[w][lg*4 + i][16 + lr] = (f16)s1[i];
        }
        asm volatile("s_waitcnt lgkmcnt(0)" ::: "memory");
        f16x8 pa = *(const f16x8*)&P[w][lr][lg*8];
        #pragma unroll
        for (int f = 0; f < 8; ++f) {
            f16x8 bv = ld8(&Vb[(size_t)(f*16 + lr) * 2688 + kt + lg*8]);
            o[f] = MFMA16(pa, bv, o[f]);
        }
    }
    #pragma unroll
    for (int i = 0; i < 4; ++i) {
        float inv = 1.0f / ls[i];
        #pragma unroll
        for (int f = 0; f < 8; ++f)
            out16[(size_t)(q0 + lg*4 + i) * 2048 + h*128 + f*16 + lr] = (f16)(o[f][i] * inv);
    }
}

extern "C" void kernel_launch(void* const* d_in, const int* in_sizes, int n_in,
                              void* d_out, int out_size, void* d_ws, size_t ws_size,
                              hipStream_t stream) {
    const float* h     = (const float*)d_in[0];
    const float* wq    = (const float*)d_in[1];
    const float* wk    = (const float*)d_in[2];
    const float* wv    = (const float*)d_in[3];
    const float* wo    = (const float*)d_in[4];
    const float* qnw   = (const float*)d_in[5];
    const float* knw   = (const float*)d_in[6];
    const float* sw1   = (const float*)d_in[7];
    const float* sb1   = (const float*)d_in[8];
    const float* sw2   = (const float*)d_in[9];
    const float* sb2   = (const float*)d_in[10];
    const float* sscal = (const float*)d_in[11];
    const float* ka    = (const float*)d_in[12];
    const float* kb    = (const float*)d_in[13];
    const float* cosb  = (const float*)d_in[14];
    const float* sinb  = (const float*)d_in[15];
    float* outp = (float*)d_out;

    char* ws = (char*)d_ws;
    size_t off = 0;
    f16*    h16    = (f16*)(ws + off);   off += (size_t)4096*2048*2;      // 16.8MB
    f16*    wqkvt  = (f16*)(ws + off);   off += (size_t)3072*2048*2;      // 12.6MB
    f16*    wot    = (f16*)(ws + off);   off += (size_t)2048*2048*2;      // 8.4MB
    float*  qkvraw = (float*)(ws + off); off += (size_t)4096*3072*4;      // 50.3MB
    f16*    qr     = (f16*)(ws + off);   off += (size_t)4096*2048*2;      // 16.8MB
    float*  kn     = (float*)(ws + off); off += (size_t)4096*512*4;       // 8.4MB
    f16*    attn16 = (f16*)(ws + off);   off += (size_t)4096*2048*2;      // 16.8MB
    float*  T      = (float*)(ws + off); off += (size_t)2*32*16*512*4;    // 2MB
    f16*    Kf     = (f16*)(ws + off);   off += (size_t)4*2688*128*2;     // 2.75MB
    f16*    VfT    = (f16*)(ws + off);   off += (size_t)4*128*2688*2;     // 2.75MB
    double* logitsD= (double*)(ws + off);off += (size_t)4096*8;
    float*  iw     = (float*)(ws + off); off += (size_t)4096*4;
    int*    sel    = (int*)(ws + off);   off += (size_t)2048*4;

    // 1. hidden -> f16
    k_cvt<<<4096, 256, 0, stream>>>(h, h16);
    // 2. weight transposes -> f16 [N][K]
    k_transpose<<<dim3(64,64), dim3(32,8), 0, stream>>>(wq, wqkvt, 2048, 0);
    k_transpose<<<dim3(16,64), dim3(32,8), 0, stream>>>(wk, wqkvt, 512, 2048);
    k_transpose<<<dim3(16,64), dim3(32,8), 0, stream>>>(wv, wqkvt, 512, 2560);
    k_transpose<<<dim3(64,64), dim3(32,8), 0, stream>>>(wo, wot, 2048, 0);
    // 3. gating MLP (f64) -> logits, iw
    k_mlp<<<1024, 256, 0, stream>>>(h, sw1, sb1, sw2, sb2, logitsD, iw);
    // 4. top-2048 selection
    k_topk<<<1, 1024, 0, stream>>>(logitsD, sel);
    // 5. fused QKV GEMM (f16 MFMA, f32 out)
    k_gemm<<<dim3(24,32), 256, 0, stream>>>(h16, wqkvt, qkvraw, 4096, 3072, 2048);
    // 6. q norm + rope (+1/sqrt(128)) -> f16
    k_normq<<<4096, 256, 0, stream>>>(qkvraw, qnw, cosb, sinb, qr);
    // 7. k norm -> f32
    k_normk<<<4096, 64, 0, stream>>>(qkvraw, knw, kn);
    // 8. gather detail K (roped) and V
    k_gather<<<2048, 128, 0, stream>>>(sel, kn, qkvraw, cosb, sinb, Kf, VfT);
    // 9-10. kron sketch
    k_sketch1<<<dim3(512,2), 256, 0, stream>>>(kn, qkvraw, iw, kb, T);
    k_sketch2<<<dim3(640,2), 256, 0, stream>>>(T, ka, sscal, Kf, VfT);
    // 11. attention
    k_attn<<<dim3(64,16), 256, 0, stream>>>(qr, Kf, VfT, attn16);
    // 12. output projection
    k_gemm<<<dim3(16,32), 256, 0, stream>>>(attn16, wot, outp, 4096, 2048, 2048);
}

// Round 2
// 980.634 us; speedup vs baseline: 1.0609x; 1.0609x over previous
//
#include <hip/hip_runtime.h>
#include <math.h>

typedef _Float16 f16;
typedef f16 f16x8 __attribute__((ext_vector_type(8)));
typedef float f32x4 __attribute__((ext_vector_type(4)));

#define MFMA16(a,b,c) __builtin_amdgcn_mfma_f32_16x16x32_f16(a,b,c,0,0,0)

static __device__ __forceinline__ f16x8 ld8(const f16* p) { return *(const f16x8*)p; }

static __device__ __forceinline__ float exp2a(float x) {
    float r; asm("v_exp_f32 %0, %1" : "=v"(r) : "v"(x)); return r;
}

#if __has_builtin(__builtin_amdgcn_global_load_lds)
#define GLL16(g, lptr) __builtin_amdgcn_global_load_lds((const __attribute__((address_space(1))) void*)(g), (__attribute__((address_space(3))) void*)(lptr), 16, 0, 0)
#define HAVE_GLL 1
#endif

// ---------------- f32 -> f16 convert (8 elems/thread) ----------------
__global__ __launch_bounds__(256) void k_cvt(const float* __restrict__ in, f16* __restrict__ out) {
    int idx = blockIdx.x * 256 + threadIdx.x;
    int base = idx * 8;
    float4 a = *(const float4*)&in[base];
    float4 b = *(const float4*)&in[base + 4];
    f16x8 v;
    v[0]=(f16)a.x; v[1]=(f16)a.y; v[2]=(f16)a.z; v[3]=(f16)a.w;
    v[4]=(f16)b.x; v[5]=(f16)b.y; v[6]=(f16)b.z; v[7]=(f16)b.w;
    *(f16x8*)&out[base] = v;
}

// ---------------- transpose f32 [K=2048][inCols] -> f16 [inCols][2048] (row offset) ----------------
__global__ __launch_bounds__(256) void k_transpose(const float* __restrict__ in, f16* __restrict__ out,
                                                   int inCols, int rowOff) {
    __shared__ float tile[32][33];
    int tx = threadIdx.x, ty = threadIdx.y;
    int x = blockIdx.x * 32 + tx;
    int y0 = blockIdx.y * 32;
    #pragma unroll
    for (int i = 0; i < 4; ++i)
        tile[ty + i*8][tx] = in[(size_t)(y0 + ty + i*8) * inCols + x];
    __syncthreads();
    #pragma unroll
    for (int i = 0; i < 4; ++i)
        out[(size_t)(rowOff + blockIdx.x*32 + ty + i*8) * 2048 + y0 + tx] = (f16)tile[tx][ty + i*8];
}

// ---------------- gating MLP in f64: logits + iw ----------------
__global__ __launch_bounds__(256) void k_mlp(const float* __restrict__ h, const float* __restrict__ w1,
                                             const float* __restrict__ b1, const float* __restrict__ w2,
                                             const float* __restrict__ b2, double* __restrict__ logitsD,
                                             float* __restrict__ iw) {
    __shared__ float hl[4 * 2048];
    __shared__ double tl[4][64];
    int tid = threadIdx.x;
    int s0 = blockIdx.x * 4;
    #pragma unroll
    for (int p = 0; p < 8; ++p) {
        int off = p * 1024 + tid * 4;
        *(float4*)&hl[off] = *(const float4*)&h[(size_t)s0 * 2048 + off];
    }
    __syncthreads();
    int j = tid & 63, r = tid >> 6;
    const float* hr = &hl[r * 2048];
    double acc = 0.0;
    for (int c = 0; c < 2048; ++c) acc += (double)hr[c] * (double)w1[c * 64 + j];
    acc += (double)b1[j];
    tl[r][j] = tanh(acc);
    __syncthreads();
    int lane = tid & 63, rr = tid >> 6;
    double v = tl[rr][lane] * (double)w2[lane];
    for (int o = 32; o > 0; o >>= 1) v += __shfl_down(v, o);
    if (lane == 0) {
        double lg = v + (double)b2[0] - 1.8562979903656263; // log(4096/640)
        logitsD[s0 + rr] = lg;
        iw[s0 + rr] = (float)(1.0 / (1.0 + exp(-lg)));
    }
}

// ---------------- top-2048 of 4096 via single-block bitonic sort ----------------
__global__ __launch_bounds__(1024) void k_topk(const double* __restrict__ logitsD, int* __restrict__ sel) {
    __shared__ unsigned long long rv[4096];
    __shared__ int ridx[4096];
    int tid = threadIdx.x;
    for (int i = tid; i < 4096; i += 1024) {
        unsigned long long u = (unsigned long long)__double_as_longlong(logitsD[i]);
        u ^= (u >> 63) ? 0xFFFFFFFFFFFFFFFFull : 0x8000000000000000ull;
        rv[i] = ~u;
        ridx[i] = i;
    }
    __syncthreads();
    for (int k = 2; k <= 4096; k <<= 1) {
        for (int jj = k >> 1; jj > 0; jj >>= 1) {
            for (int i = tid; i < 4096; i += 1024) {
                int ij = i ^ jj;
                if (ij > i) {
                    bool up = ((i & k) == 0);
                    unsigned long long a = rv[i], b = rv[ij];
                    bool gt = (a > b) || (a == b && ridx[i] > ridx[ij]);
                    if (gt == up) {
                        rv[i] = b; rv[ij] = a;
                        int t = ridx[i]; ridx[i] = ridx[ij]; ridx[ij] = t;
                    }
                }
            }
            __syncthreads();
        }
    }
    for (int i = tid; i < 2048; i += 1024) sel[i] = ridx[i];
}

// ---------------- f16 GEMM: C[M][N] = A[M][K] * Bt[N][K]^T, f32 out ----------------
__global__ __launch_bounds__(256) void k_gemm(const f16* __restrict__ A, const f16* __restrict__ Bt,
                                              float* __restrict__ C, int M, int N, int K) {
    __shared__ f16 As[128 * 32];
    __shared__ f16 Bs[128 * 32];
    int tid = threadIdx.x;
    int w = tid >> 6, l = tid & 63, lr = l & 15, lg = l >> 4;
    int wr = w >> 1, wc = w & 1;
    int row0 = blockIdx.y * 128, col0 = blockIdx.x * 128;
    f32x4 zero = {0.f, 0.f, 0.f, 0.f};
    f32x4 acc[4][4];
    #pragma unroll
    for (int m = 0; m < 4; ++m)
        #pragma unroll
        for (int n = 0; n < 4; ++n) acc[m][n] = zero;
    for (int k0 = 0; k0 < K; k0 += 32) {
        #pragma unroll
        for (int p = 0; p < 2; ++p) {
            int id = p * 256 + tid;
            int r = id >> 2, c8 = (id & 3) * 8;
#ifdef HAVE_GLL
            GLL16(&A[(size_t)(row0 + r) * K + k0 + c8], &As[id * 8]);
            GLL16(&Bt[(size_t)(col0 + r) * K + k0 + c8], &Bs[id * 8]);
#else
            *(int4*)&As[id * 8] = *(const int4*)&A[(size_t)(row0 + r) * K + k0 + c8];
            *(int4*)&Bs[id * 8] = *(const int4*)&Bt[(size_t)(col0 + r) * K + k0 + c8];
#endif
        }
        __syncthreads();
        f16x8 a[4], b[4];
        #pragma unroll
        for (int m = 0; m < 4; ++m) a[m] = ld8(&As[(wr*64 + m*16 + lr) * 32 + lg*8]);
        #pragma unroll
        for (int n = 0; n < 4; ++n) b[n] = ld8(&Bs[(wc*64 + n*16 + lr) * 32 + lg*8]);
        #pragma unroll
        for (int m = 0; m < 4; ++m)
            #pragma unroll
            for (int n = 0; n < 4; ++n)
                acc[m][n] = MFMA16(a[m], b[n], acc[m][n]);
        __syncthreads();
    }
    #pragma unroll
    for (int m = 0; m < 4; ++m)
        #pragma unroll
        for (int n = 0; n < 4; ++n)
            #pragma unroll
            for (int i = 0; i < 4; ++i)
                C[(size_t)(row0 + wr*64 + m*16 + lg*4 + i) * N + col0 + wc*64 + n*16 + lr] = acc[m][n][i];
}

// ---------------- q: RMSnorm + RoPE + fold log2(e)/sqrt(128), f16 out ----------------
__global__ __launch_bounds__(256) void k_normq(const float* __restrict__ qkv, const float* __restrict__ qnw,
                                               const float* __restrict__ cosb, const float* __restrict__ sinb,
                                               f16* __restrict__ qr) {
    int s = blockIdx.x;
    int tid = threadIdx.x;
    int h = tid >> 4, ln = tid & 15, d0 = ln * 8;
    const float* src = &qkv[(size_t)s * 3072 + h * 128 + d0];
    float4 a = *(const float4*)src, b = *(const float4*)(src + 4);
    float x[8] = {a.x,a.y,a.z,a.w,b.x,b.y,b.z,b.w};
    float ss = 0;
    #pragma unroll
    for (int j = 0; j < 8; ++j) ss += x[j]*x[j];
    ss += __shfl_xor(ss,1); ss += __shfl_xor(ss,2); ss += __shfl_xor(ss,4); ss += __shfl_xor(ss,8);
    float rn = rsqrtf(ss * (1.0f/128.0f) + 1e-6f);
    float xn[8];
    #pragma unroll
    for (int j = 0; j < 8; ++j) xn[j] = x[j] * rn * qnw[d0 + j];
    const float scl = 0.088388347648318447f * 1.4426950408889634f; // log2(e)/sqrt(128)
    f16x8 o;
    #pragma unroll
    for (int j = 0; j < 8; ++j) {
        float pr = __shfl_xor(xn[j], 8);
        float rot = (ln < 8) ? -pr : pr;
        int d = d0 + j;
        o[j] = (f16)((xn[j]*cosb[s*128 + d] + rot*sinb[s*128 + d]) * scl);
    }
    *(f16x8*)&qr[(size_t)s * 2048 + h * 128 + d0] = o;
}

// ---------------- k: RMSnorm, f32 out ----------------
__global__ __launch_bounds__(64) void k_normk(const float* __restrict__ qkv, const float* __restrict__ knw,
                                              float* __restrict__ kn) {
    int s = blockIdx.x;
    int tid = threadIdx.x;
    int h = tid >> 4, ln = tid & 15, d0 = ln * 8;
    const float* src = &qkv[(size_t)s * 3072 + 2048 + h * 128 + d0];
    float4 a = *(const float4*)src, b = *(const float4*)(src + 4);
    float x[8] = {a.x,a.y,a.z,a.w,b.x,b.y,b.z,b.w};
    float ss = 0;
    #pragma unroll
    for (int j = 0; j < 8; ++j) ss += x[j]*x[j];
    ss += __shfl_xor(ss,1); ss += __shfl_xor(ss,2); ss += __shfl_xor(ss,4); ss += __shfl_xor(ss,8);
    float rn = rsqrtf(ss * (1.0f/128.0f) + 1e-6f);
    float o[8];
    #pragma unroll
    for (int j = 0; j < 8; ++j) o[j] = x[j] * rn * knw[d0 + j];
    float* dst = &kn[(size_t)s*512 + h*128 + d0];
    *(float4*)dst = make_float4(o[0],o[1],o[2],o[3]);
    *(float4*)(dst+4) = make_float4(o[4],o[5],o[6],o[7]);
}

// ---------------- gather detail keys (rope) + values ----------------
__global__ __launch_bounds__(128) void k_gather(const int* __restrict__ sel, const float* __restrict__ kn,
                                                const float* __restrict__ qkv, const float* __restrict__ cosb,
                                                const float* __restrict__ sinb, f16* __restrict__ Kf,
                                                f16* __restrict__ VfT) {
    int j = blockIdx.x;
    int s = sel[j];
    int t = threadIdx.x; // 0..127
    float c = cosb[s*128 + t], sn = sinb[s*128 + t];
    #pragma unroll
    for (int h = 0; h < 4; ++h) {
        float x  = kn[(size_t)s*512 + h*128 + t];
        float pr = kn[(size_t)s*512 + h*128 + (t ^ 64)];
        float rot = (t < 64) ? -pr : pr;
        Kf[(size_t)(h*2688 + j) * 128 + t] = (f16)(x*c + rot*sn);
        float v = qkv[(size_t)s*3072 + 2560 + h*128 + t];
        VfT[(size_t)h*128*2688 + (size_t)t*2688 + j] = (f16)v;
    }
}

// ---------------- sketch stage 1 ----------------
__global__ __launch_bounds__(256) void k_sketch1(const float* __restrict__ kn, const float* __restrict__ qkv,
                                                 const float* __restrict__ iw, const float* __restrict__ kronb,
                                                 float* __restrict__ T) {
    int mb = blockIdx.x & 31, sa = blockIdx.x >> 5;
    int which = blockIdx.y;
    int c0 = threadIdx.x * 2;
    float a0 = 0, a1 = 0;
    for (int sb = 0; sb < 256; ++sb) {
        int s = sa * 256 + sb;
        float wgt = kronb[mb * 256 + sb] * iw[s];
        const float* src = which ? &qkv[(size_t)s*3072 + 2560] : &kn[(size_t)s*512];
        a0 += wgt * src[c0];
        a1 += wgt * src[c0 + 1];
    }
    float* dst = &T[(size_t)((which*32 + mb)*16 + sa) * 512 + c0];
    dst[0] = a0; dst[1] = a1;
}

// ---------------- sketch stage 2 ----------------
__global__ __launch_bounds__(256) void k_sketch2(const float* __restrict__ T, const float* __restrict__ krona,
                                                 const float* __restrict__ sscale, f16* __restrict__ Kf,
                                                 f16* __restrict__ VfT) {
    int m = blockIdx.x;
    int which = blockIdx.y;
    int ma = m >> 5, mb = m & 31;
    int c0 = threadIdx.x * 2;
    float sc = sscale[0];
    float a0 = 0, a1 = 0;
    #pragma unroll
    for (int sa = 0; sa < 16; ++sa) {
        float ka = krona[ma * 128 + sa];
        const float* t = &T[(size_t)((which*32 + mb)*16 + sa) * 512 + c0];
        a0 += ka * t[0];
        a1 += ka * t[1];
    }
    a0 *= sc; a1 *= sc;
    int key = 2048 + m;
    int h0 = c0 >> 7, d = c0 & 127;
    if (which == 0) {
        Kf[(size_t)(h0*2688 + key)*128 + d]     = (f16)a0;
        Kf[(size_t)(h0*2688 + key)*128 + d + 1] = (f16)a1;
    } else {
        VfT[(size_t)h0*128*2688 + (size_t)d*2688 + key]       = (f16)a0;
        VfT[(size_t)h0*128*2688 + (size_t)(d+1)*2688 + key]   = (f16)a1;
    }
}

// ---------------- flash attention: KVBLK=64, exp2, deferred rescale ----------------
__global__ __launch_bounds__(256, 4) void k_attn(const f16* __restrict__ qr, const f16* __restrict__ Kf,
                                                 const f16* __restrict__ VfT, f16* __restrict__ out16) {
    __shared__ f16 P[4][16][72];   // 72 = 64 + 8 pad (keeps 16B align, skews banks)
    int qt = blockIdx.x, h = blockIdx.y;
    int kvh = h >> 2;
    int tid = threadIdx.x;
    int w = tid >> 6, l = tid & 63, lr = l & 15, lg = l >> 4;
    int q0 = qt * 64 + w * 16;
    const f16* Kb = Kf + (size_t)kvh * 2688 * 128;
    const f16* Vb = VfT + (size_t)kvh * 128 * 2688;
    f16x8 aq[4];
    #pragma unroll
    for (int c = 0; c < 4; ++c)
        aq[c] = ld8(&qr[(size_t)(q0 + lr) * 2048 + h*128 + c*32 + lg*8]);
    f32x4 zero = {0.f,0.f,0.f,0.f};
    f32x4 o[8];
    #pragma unroll
    for (int f = 0; f < 8; ++f) o[f] = zero;
    float m[4], lsp[4];
    #pragma unroll
    for (int i = 0; i < 4; ++i) { m[i] = -1e30f; lsp[i] = 0.f; }

    for (int kt = 0; kt < 2688; kt += 64) {
        f32x4 s[4];
        #pragma unroll
        for (int t = 0; t < 4; ++t) s[t] = zero;
        #pragma unroll
        for (int t = 0; t < 4; ++t)
            #pragma unroll
            for (int c = 0; c < 4; ++c)
                s[t] = MFMA16(aq[c], ld8(&Kb[(size_t)(kt + t*16 + lr) * 128 + c*32 + lg*8]), s[t]);
        // per-row tile max: in-register over 4 frags, then one 4-deep shfl chain
        float tm[4];
        #pragma unroll
        for (int i = 0; i < 4; ++i) {
            float a = fmaxf(fmaxf(s[0][i], s[1][i]), fmaxf(s[2][i], s[3][i]));
            a = fmaxf(a, __shfl_xor(a, 1));
            a = fmaxf(a, __shfl_xor(a, 2));
            a = fmaxf(a, __shfl_xor(a, 4));
            a = fmaxf(a, __shfl_xor(a, 8));
            tm[i] = a;
        }
        bool need = (tm[0] > m[0]+8.f)||(tm[1] > m[1]+8.f)||(tm[2] > m[2]+8.f)||(tm[3] > m[3]+8.f);
        if (__any(need)) {
            f32x4 cfv;
            #pragma unroll
            for (int i = 0; i < 4; ++i) {
                float mn = fmaxf(m[i], tm[i]);
                float cf = exp2a(m[i] - mn);
                m[i] = mn; lsp[i] *= cf; cfv[i] = cf;
            }
            #pragma unroll
            for (int f = 0; f < 8; ++f) o[f] *= cfv;
        }
        #pragma unroll
        for (int t = 0; t < 4; ++t)
            #pragma unroll
            for (int i = 0; i < 4; ++i) {
                float p = exp2a(s[t][i] - m[i]);
                lsp[i] += p;
                P[w][lg*4 + i][t*16 + lr] = (f16)p;
            }
        asm volatile("s_waitcnt lgkmcnt(0)" ::: "memory");
        __builtin_amdgcn_sched_barrier(0);
        #pragma unroll
        for (int kw = 0; kw < 2; ++kw) {
            f16x8 pa = *(const f16x8*)&P[w][lr][kw*32 + lg*8];
            #pragma unroll
            for (int f = 0; f < 8; ++f)
                o[f] = MFMA16(pa, ld8(&Vb[(size_t)(f*16 + lr) * 2688 + kt + kw*32 + lg*8]), o[f]);
        }
    }
    #pragma unroll
    for (int i = 0; i < 4; ++i) {
        float ls = lsp[i];
        ls += __shfl_xor(ls, 1); ls += __shfl_xor(ls, 2);
        ls += __shfl_xor(ls, 4); ls += __shfl_xor(ls, 8);
        float inv = 1.0f / ls;
        #pragma unroll
        for (int f = 0; f < 8; ++f)
            out16[(size_t)(q0 + lg*4 + i) * 2048 + h*128 + f*16 + lr] = (f16)(o[f][i] * inv);
    }
}

extern "C" void kernel_launch(void* const* d_in, const int* in_sizes, int n_in,
                              void* d_out, int out_size, void* d_ws, size_t ws_size,
                              hipStream_t stream) {
    const float* h     = (const float*)d_in[0];
    const float* wq    = (const float*)d_in[1];
    const float* wk    = (const float*)d_in[2];
    const float* wv    = (const float*)d_in[3];
    const float* wo    = (const float*)d_in[4];
    const float* qnw   = (const float*)d_in[5];
    const float* knw   = (const float*)d_in[6];
    const float* sw1   = (const float*)d_in[7];
    const float* sb1   = (const float*)d_in[8];
    const float* sw2   = (const float*)d_in[9];
    const float* sb2   = (const float*)d_in[10];
    const float* sscal = (const float*)d_in[11];
    const float* ka    = (const float*)d_in[12];
    const float* kb    = (const float*)d_in[13];
    const float* cosb  = (const float*)d_in[14];
    const float* sinb  = (const float*)d_in[15];
    float* outp = (float*)d_out;

    char* ws = (char*)d_ws;
    size_t off = 0;
    f16*    h16    = (f16*)(ws + off);   off += (size_t)4096*2048*2;
    f16*    wqkvt  = (f16*)(ws + off);   off += (size_t)3072*2048*2;
    f16*    wot    = (f16*)(ws + off);   off += (size_t)2048*2048*2;
    float*  qkvraw = (float*)(ws + off); off += (size_t)4096*3072*4;
    f16*    qr     = (f16*)(ws + off);   off += (size_t)4096*2048*2;
    float*  kn     = (float*)(ws + off); off += (size_t)4096*512*4;
    f16*    attn16 = (f16*)(ws + off);   off += (size_t)4096*2048*2;
    float*  T      = (float*)(ws + off); off += (size_t)2*32*16*512*4;
    f16*    Kf     = (f16*)(ws + off);   off += (size_t)4*2688*128*2;
    f16*    VfT    = (f16*)(ws + off);   off += (size_t)4*128*2688*2;
    double* logitsD= (double*)(ws + off);off += (size_t)4096*8;
    float*  iw     = (float*)(ws + off); off += (size_t)4096*4;
    int*    sel    = (int*)(ws + off);   off += (size_t)2048*4;

    k_cvt<<<4096, 256, 0, stream>>>(h, h16);
    k_transpose<<<dim3(64,64), dim3(32,8), 0, stream>>>(wq, wqkvt, 2048, 0);
    k_transpose<<<dim3(16,64), dim3(32,8), 0, stream>>>(wk, wqkvt, 512, 2048);
    k_transpose<<<dim3(16,64), dim3(32,8), 0, stream>>>(wv, wqkvt, 512, 2560);
    k_transpose<<<dim3(64,64), dim3(32,8), 0, stream>>>(wo, wot, 2048, 0);
    k_mlp<<<1024, 256, 0, stream>>>(h, sw1, sb1, sw2, sb2, logitsD, iw);
    k_topk<<<1, 1024, 0, stream>>>(logitsD, sel);
    k_gemm<<<dim3(24,32), 256, 0, stream>>>(h16, wqkvt, qkvraw, 4096, 3072, 2048);
    k_normq<<<4096, 256, 0, stream>>>(qkvraw, qnw, cosb, sinb, qr);
    k_normk<<<4096, 64, 0, stream>>>(qkvraw, knw, kn);
    k_gather<<<2048, 128, 0, stream>>>(sel, kn, qkvraw, cosb, sinb, Kf, VfT);
    k_sketch1<<<dim3(512,2), 256, 0, stream>>>(kn, qkvraw, iw, kb, T);
    k_sketch2<<<dim3(640,2), 256, 0, stream>>>(T, ka, sscal, Kf, VfT);
    k_attn<<<dim3(64,16), 256, 0, stream>>>(qr, Kf, VfT, attn16);
    k_gemm<<<dim3(16,32), 256, 0, stream>>>(attn16, wot, outp, 4096, 2048, 2048);
}

// Round 3
// 529.990 us; speedup vs baseline: 1.9630x; 1.8503x over previous
//
#include <hip/hip_runtime.h>
#include <math.h>

typedef _Float16 f16;
typedef f16 f16x8 __attribute__((ext_vector_type(8)));
typedef float f32x4 __attribute__((ext_vector_type(4)));

#define MFMA16(a,b,c) __builtin_amdgcn_mfma_f32_16x16x32_f16(a,b,c,0,0,0)

static __device__ __forceinline__ f16x8 ld8(const f16* p) { return *(const f16x8*)p; }

static __device__ __forceinline__ float exp2a(float x) {
    float r; asm("v_exp_f32 %0, %1" : "=v"(r) : "v"(x)); return r;
}

#if __has_builtin(__builtin_amdgcn_global_load_lds)
#define GLL16(g, lptr) __builtin_amdgcn_global_load_lds((const __attribute__((address_space(1))) void*)(g), (__attribute__((address_space(3))) void*)(lptr), 16, 0, 0)
#else
#define GLL16(g, lptr) do { *(int4*)(lptr) = *(const int4*)(g); } while (0)
#endif

// ---------------- f32 -> f16 convert (8 elems/thread) ----------------
__global__ __launch_bounds__(256) void k_cvt(const float* __restrict__ in, f16* __restrict__ out) {
    int idx = blockIdx.x * 256 + threadIdx.x;
    int base = idx * 8;
    float4 a = *(const float4*)&in[base];
    float4 b = *(const float4*)&in[base + 4];
    f16x8 v;
    v[0]=(f16)a.x; v[1]=(f16)a.y; v[2]=(f16)a.z; v[3]=(f16)a.w;
    v[4]=(f16)b.x; v[5]=(f16)b.y; v[6]=(f16)b.z; v[7]=(f16)b.w;
    *(f16x8*)&out[base] = v;
}

// ---------------- transpose f32 [K=2048][inCols] -> f16 [inCols][2048] ----------------
__global__ __launch_bounds__(256) void k_transpose(const float* __restrict__ in, f16* __restrict__ out,
                                                   int inCols, int rowOff) {
    __shared__ float tile[32][33];
    int tx = threadIdx.x, ty = threadIdx.y;
    int x = blockIdx.x * 32 + tx;
    int y0 = blockIdx.y * 32;
    #pragma unroll
    for (int i = 0; i < 4; ++i)
        tile[ty + i*8][tx] = in[(size_t)(y0 + ty + i*8) * inCols + x];
    __syncthreads();
    #pragma unroll
    for (int i = 0; i < 4; ++i)
        out[(size_t)(rowOff + blockIdx.x*32 + ty + i*8) * 2048 + y0 + tx] = (f16)tile[tx][ty + i*8];
}

// ---------------- gating MLP in f64: logits + iw ----------------
__global__ __launch_bounds__(256) void k_mlp(const float* __restrict__ h, const float* __restrict__ w1,
                                             const float* __restrict__ b1, const float* __restrict__ w2,
                                             const float* __restrict__ b2, double* __restrict__ logitsD,
                                             float* __restrict__ iw) {
    __shared__ float hl[4 * 2048];
    __shared__ double tl[4][64];
    int tid = threadIdx.x;
    int s0 = blockIdx.x * 4;
    #pragma unroll
    for (int p = 0; p < 8; ++p) {
        int off = p * 1024 + tid * 4;
        *(float4*)&hl[off] = *(const float4*)&h[(size_t)s0 * 2048 + off];
    }
    __syncthreads();
    int j = tid & 63, r = tid >> 6;
    const float* hr = &hl[r * 2048];
    double acc = 0.0;
    for (int c = 0; c < 2048; ++c) acc += (double)hr[c] * (double)w1[c * 64 + j];
    acc += (double)b1[j];
    tl[r][j] = tanh(acc);
    __syncthreads();
    int lane = tid & 63, rr = tid >> 6;
    double v = tl[rr][lane] * (double)w2[lane];
    for (int o = 32; o > 0; o >>= 1) v += __shfl_down(v, o);
    if (lane == 0) {
        double lg = v + (double)b2[0] - 1.8562979903656263; // log(4096/640)
        logitsD[s0 + rr] = lg;
        iw[s0 + rr] = (float)(1.0 / (1.0 + exp(-lg)));
    }
}

// ---------------- top-2048 of 4096 via single-block bitonic sort ----------------
__global__ __launch_bounds__(1024) void k_topk(const double* __restrict__ logitsD, int* __restrict__ sel) {
    __shared__ unsigned long long rv[4096];
    __shared__ int ridx[4096];
    int tid = threadIdx.x;
    for (int i = tid; i < 4096; i += 1024) {
        unsigned long long u = (unsigned long long)__double_as_longlong(logitsD[i]);
        u ^= (u >> 63) ? 0xFFFFFFFFFFFFFFFFull : 0x8000000000000000ull;
        rv[i] = ~u;
        ridx[i] = i;
    }
    __syncthreads();
    for (int k = 2; k <= 4096; k <<= 1) {
        for (int jj = k >> 1; jj > 0; jj >>= 1) {
            for (int i = tid; i < 4096; i += 1024) {
                int ij = i ^ jj;
                if (ij > i) {
                    bool up = ((i & k) == 0);
                    unsigned long long a = rv[i], b = rv[ij];
                    bool gt = (a > b) || (a == b && ridx[i] > ridx[ij]);
                    if (gt == up) {
                        rv[i] = b; rv[ij] = a;
                        int t = ridx[i]; ridx[i] = ridx[ij]; ridx[ij] = t;
                    }
                }
            }
            __syncthreads();
        }
    }
    for (int i = tid; i < 2048; i += 1024) sel[i] = ridx[i];
}

// ---------------- f16 GEMM: C[M][N] = A[M][K] * Bt[N][K]^T, f32 out ----------------
__global__ __launch_bounds__(256) void k_gemm(const f16* __restrict__ A, const f16* __restrict__ Bt,
                                              float* __restrict__ C, int M, int N, int K) {
    __shared__ f16 As[128 * 32];
    __shared__ f16 Bs[128 * 32];
    int tid = threadIdx.x;
    int w = tid >> 6, l = tid & 63, lr = l & 15, lg = l >> 4;
    int wr = w >> 1, wc = w & 1;
    int row0 = blockIdx.y * 128, col0 = blockIdx.x * 128;
    f32x4 zero = {0.f, 0.f, 0.f, 0.f};
    f32x4 acc[4][4];
    #pragma unroll
    for (int m = 0; m < 4; ++m)
        #pragma unroll
        for (int n = 0; n < 4; ++n) acc[m][n] = zero;
    for (int k0 = 0; k0 < K; k0 += 32) {
        #pragma unroll
        for (int p = 0; p < 2; ++p) {
            int id = p * 256 + tid;
            int r = id >> 2, c8 = (id & 3) * 8;
            GLL16(&A[(size_t)(row0 + r) * K + k0 + c8], &As[id * 8]);
            GLL16(&Bt[(size_t)(col0 + r) * K + k0 + c8], &Bs[id * 8]);
        }
        __syncthreads();
        f16x8 a[4], b[4];
        #pragma unroll
        for (int m = 0; m < 4; ++m) a[m] = ld8(&As[(wr*64 + m*16 + lr) * 32 + lg*8]);
        #pragma unroll
        for (int n = 0; n < 4; ++n) b[n] = ld8(&Bs[(wc*64 + n*16 + lr) * 32 + lg*8]);
        #pragma unroll
        for (int m = 0; m < 4; ++m)
            #pragma unroll
            for (int n = 0; n < 4; ++n)
                acc[m][n] = MFMA16(a[m], b[n], acc[m][n]);
        __syncthreads();
    }
    #pragma unroll
    for (int m = 0; m < 4; ++m)
        #pragma unroll
        for (int n = 0; n < 4; ++n)
            #pragma unroll
            for (int i = 0; i < 4; ++i)
                C[(size_t)(row0 + wr*64 + m*16 + lg*4 + i) * N + col0 + wc*64 + n*16 + lr] = acc[m][n][i];
}

// ---------------- q: RMSnorm + RoPE + fold log2(e)/sqrt(128), f16 out ----------------
__global__ __launch_bounds__(256) void k_normq(const float* __restrict__ qkv, const float* __restrict__ qnw,
                                               const float* __restrict__ cosb, const float* __restrict__ sinb,
                                               f16* __restrict__ qr) {
    int s = blockIdx.x;
    int tid = threadIdx.x;
    int h = tid >> 4, ln = tid & 15, d0 = ln * 8;
    const float* src = &qkv[(size_t)s * 3072 + h * 128 + d0];
    float4 a = *(const float4*)src, b = *(const float4*)(src + 4);
    float x[8] = {a.x,a.y,a.z,a.w,b.x,b.y,b.z,b.w};
    float ss = 0;
    #pragma unroll
    for (int j = 0; j < 8; ++j) ss += x[j]*x[j];
    ss += __shfl_xor(ss,1); ss += __shfl_xor(ss,2); ss += __shfl_xor(ss,4); ss += __shfl_xor(ss,8);
    float rn = rsqrtf(ss * (1.0f/128.0f) + 1e-6f);
    float xn[8];
    #pragma unroll
    for (int j = 0; j < 8; ++j) xn[j] = x[j] * rn * qnw[d0 + j];
    const float scl = 0.088388347648318447f * 1.4426950408889634f; // log2(e)/sqrt(128)
    f16x8 o;
    #pragma unroll
    for (int j = 0; j < 8; ++j) {
        float pr = __shfl_xor(xn[j], 8);
        float rot = (ln < 8) ? -pr : pr;
        int d = d0 + j;
        o[j] = (f16)((xn[j]*cosb[s*128 + d] + rot*sinb[s*128 + d]) * scl);
    }
    *(f16x8*)&qr[(size_t)s * 2048 + h * 128 + d0] = o;
}

// ---------------- k: RMSnorm, f32 out ----------------
__global__ __launch_bounds__(64) void k_normk(const float* __restrict__ qkv, const float* __restrict__ knw,
                                              float* __restrict__ kn) {
    int s = blockIdx.x;
    int tid = threadIdx.x;
    int h = tid >> 4, ln = tid & 15, d0 = ln * 8;
    const float* src = &qkv[(size_t)s * 3072 + 2048 + h * 128 + d0];
    float4 a = *(const float4*)src, b = *(const float4*)(src + 4);
    float x[8] = {a.x,a.y,a.z,a.w,b.x,b.y,b.z,b.w};
    float ss = 0;
    #pragma unroll
    for (int j = 0; j < 8; ++j) ss += x[j]*x[j];
    ss += __shfl_xor(ss,1); ss += __shfl_xor(ss,2); ss += __shfl_xor(ss,4); ss += __shfl_xor(ss,8);
    float rn = rsqrtf(ss * (1.0f/128.0f) + 1e-6f);
    float o[8];
    #pragma unroll
    for (int j = 0; j < 8; ++j) o[j] = x[j] * rn * knw[d0 + j];
    float* dst = &kn[(size_t)s*512 + h*128 + d0];
    *(float4*)dst = make_float4(o[0],o[1],o[2],o[3]);
    *(float4*)(dst+4) = make_float4(o[4],o[5],o[6],o[7]);
}

// ---------------- gather detail keys (rope) + values ----------------
__global__ __launch_bounds__(128) void k_gather(const int* __restrict__ sel, const float* __restrict__ kn,
                                                const float* __restrict__ qkv, const float* __restrict__ cosb,
                                                const float* __restrict__ sinb, f16* __restrict__ Kf,
                                                f16* __restrict__ VfT) {
    int j = blockIdx.x;
    int s = sel[j];
    int t = threadIdx.x; // 0..127
    float c = cosb[s*128 + t], sn = sinb[s*128 + t];
    #pragma unroll
    for (int h = 0; h < 4; ++h) {
        float x  = kn[(size_t)s*512 + h*128 + t];
        float pr = kn[(size_t)s*512 + h*128 + (t ^ 64)];
        float rot = (t < 64) ? -pr : pr;
        Kf[(size_t)(h*2688 + j) * 128 + t] = (f16)(x*c + rot*sn);
        float v = qkv[(size_t)s*3072 + 2560 + h*128 + t];
        VfT[(size_t)h*128*2688 + (size_t)t*2688 + j] = (f16)v;
    }
}

// ---------------- sketch stage 1 ----------------
__global__ __launch_bounds__(256) void k_sketch1(const float* __restrict__ kn, const float* __restrict__ qkv,
                                                 const float* __restrict__ iw, const float* __restrict__ kronb,
                                                 float* __restrict__ T) {
    int mb = blockIdx.x & 31, sa = blockIdx.x >> 5;
    int which = blockIdx.y;
    int c0 = threadIdx.x * 2;
    float a0 = 0, a1 = 0;
    for (int sb = 0; sb < 256; ++sb) {
        int s = sa * 256 + sb;
        float wgt = kronb[mb * 256 + sb] * iw[s];
        const float* src = which ? &qkv[(size_t)s*3072 + 2560] : &kn[(size_t)s*512];
        a0 += wgt * src[c0];
        a1 += wgt * src[c0 + 1];
    }
    float* dst = &T[(size_t)((which*32 + mb)*16 + sa) * 512 + c0];
    dst[0] = a0; dst[1] = a1;
}

// ---------------- sketch stage 2 ----------------
__global__ __launch_bounds__(256) void k_sketch2(const float* __restrict__ T, const float* __restrict__ krona,
                                                 const float* __restrict__ sscale, f16* __restrict__ Kf,
                                                 f16* __restrict__ VfT) {
    int m = blockIdx.x;
    int which = blockIdx.y;
    int ma = m >> 5, mb = m & 31;
    int c0 = threadIdx.x * 2;
    float sc = sscale[0];
    float a0 = 0, a1 = 0;
    #pragma unroll
    for (int sa = 0; sa < 16; ++sa) {
        float ka = krona[ma * 128 + sa];
        const float* t = &T[(size_t)((which*32 + mb)*16 + sa) * 512 + c0];
        a0 += ka * t[0];
        a1 += ka * t[1];
    }
    a0 *= sc; a1 *= sc;
    int key = 2048 + m;
    int h0 = c0 >> 7, d = c0 & 127;
    if (which == 0) {
        Kf[(size_t)(h0*2688 + key)*128 + d]     = (f16)a0;
        Kf[(size_t)(h0*2688 + key)*128 + d + 1] = (f16)a1;
    } else {
        VfT[(size_t)h0*128*2688 + (size_t)d*2688 + key]       = (f16)a0;
        VfT[(size_t)h0*128*2688 + (size_t)(d+1)*2688 + key]   = (f16)a1;
    }
}

// ---------------- flash attention v3: LDS-staged K/V, 8 waves x 32 q-rows ----------------
// LDS tiles: KT[64 keys][128 d] (swizzled bcol^=(row&7)<<5), VT[128 d][64 keys] (bcol^=(d&7)<<4).
// Staged via global_load_lds: linear LDS dest, inverse-swizzled global source (rule #21).
__global__ __launch_bounds__(512, 2) void k_attn(const f16* __restrict__ qr, const f16* __restrict__ Kf,
                                                 const f16* __restrict__ VfT, f16* __restrict__ out16) {
    __shared__ f16 KT[2][64 * 128];
    __shared__ f16 VT[2][128 * 64];
    __shared__ f16 P[8][32][72];
    int qt = blockIdx.x, h = blockIdx.y;
    int kvh = h >> 2;
    int tid = threadIdx.x;
    int w = tid >> 6, l = tid & 63, lr = l & 15, lg = l >> 4;
    int q0 = qt * 256 + w * 32;
    const char* Kb = (const char*)(Kf + (size_t)kvh * 2688 * 128);
    const char* Vb = (const char*)(VfT + (size_t)kvh * 128 * 2688);

    // read-side swizzled column offsets (bytes)
    int koff[4], voff[2];
    #pragma unroll
    for (int c = 0; c < 4; ++c) koff[c] = (c*64 + lg*16) ^ ((lr & 7) << 5);
    #pragma unroll
    for (int kw = 0; kw < 2; ++kw) voff[kw] = (kw*64 + lg*16) ^ ((lr & 7) << 4);

    // staging constants: this wave stages LDS bytes [w*2048, (w+1)*2048) of each tile
    int L0 = w * 2048 + l * 16;

    f16x8 aq[2][4];
    #pragma unroll
    for (int hh = 0; hh < 2; ++hh)
        #pragma unroll
        for (int c = 0; c < 4; ++c)
            aq[hh][c] = ld8(&qr[(size_t)(q0 + hh*16 + lr) * 2048 + h*128 + c*32 + lg*8]);

    f32x4 zero = {0.f,0.f,0.f,0.f};
    f32x4 o0[8], o1[8];
    #pragma unroll
    for (int f = 0; f < 8; ++f) { o0[f] = zero; o1[f] = zero; }
    float m0[4], m1[4], ls0[4], ls1[4];
    #pragma unroll
    for (int i = 0; i < 4; ++i) { m0[i] = -1e30f; m1[i] = -1e30f; ls0[i] = 0.f; ls1[i] = 0.f; }

    // ---- staging: issue 2 K-loads + 2 V-loads (1KB each) for this wave's slice ----
    #define STAGE(buf, kt)  do {                                                          \
        _Pragma("unroll")                                                                  \
        for (int i_ = 0; i_ < 2; ++i_) {                                                   \
            int L = L0 + i_*1024;                                                          \
            int krow = L >> 8, kbc = L & 255;                                              \
            GLL16(Kb + (size_t)((kt) + krow)*256 + (kbc ^ ((krow & 7) << 5)),              \
                  (char*)&KT[buf][0] + L);                                                 \
            int vd = L >> 7, vbc = L & 127;                                                \
            GLL16(Vb + (size_t)vd*5376 + (size_t)(kt)*2 + (vbc ^ ((vd & 7) << 4)),         \
                  (char*)&VT[buf][0] + L);                                                 \
        }                                                                                  \
    } while (0)

    STAGE(0, 0);
    asm volatile("s_waitcnt vmcnt(0)" ::: "memory");
    __syncthreads();

    for (int t = 0; t < 42; ++t) {
        int cur = t & 1;
        if (t < 41) STAGE(cur ^ 1, (t + 1) * 64);
        const char* Kc = (const char*)&KT[cur][0];
        const char* Vc = (const char*)&VT[cur][0];

        // ---- QK^T: 16 shared K-frag loads, 32 MFMAs ----
        f32x4 s0[4], s1[4];
        #pragma unroll
        for (int tt = 0; tt < 4; ++tt) { s0[tt] = zero; s1[tt] = zero; }
        #pragma unroll
        for (int tt = 0; tt < 4; ++tt) {
            #pragma unroll
            for (int c = 0; c < 4; ++c) {
                f16x8 kb = ld8((const f16*)(Kc + (tt*16 + lr)*256 + koff[c]));
                s0[tt] = MFMA16(aq[0][c], kb, s0[tt]);
                s1[tt] = MFMA16(aq[1][c], kb, s1[tt]);
            }
        }

        // ---- online softmax (deferred rescale, log2 domain) ----
        float tm0[4], tm1[4];
        #pragma unroll
        for (int i = 0; i < 4; ++i) {
            float a = fmaxf(fmaxf(s0[0][i], s0[1][i]), fmaxf(s0[2][i], s0[3][i]));
            a = fmaxf(a, __shfl_xor(a, 1)); a = fmaxf(a, __shfl_xor(a, 2));
            a = fmaxf(a, __shfl_xor(a, 4)); a = fmaxf(a, __shfl_xor(a, 8));
            tm0[i] = a;
            float b = fmaxf(fmaxf(s1[0][i], s1[1][i]), fmaxf(s1[2][i], s1[3][i]));
            b = fmaxf(b, __shfl_xor(b, 1)); b = fmaxf(b, __shfl_xor(b, 2));
            b = fmaxf(b, __shfl_xor(b, 4)); b = fmaxf(b, __shfl_xor(b, 8));
            tm1[i] = b;
        }
        bool need = false;
        #pragma unroll
        for (int i = 0; i < 4; ++i) need = need || (tm0[i] > m0[i]+8.f) || (tm1[i] > m1[i]+8.f);
        if (__any(need)) {
            f32x4 cf0, cf1;
            #pragma unroll
            for (int i = 0; i < 4; ++i) {
                float mn0 = fmaxf(m0[i], tm0[i]);
                cf0[i] = exp2a(m0[i] - mn0); m0[i] = mn0; ls0[i] *= cf0[i];
                float mn1 = fmaxf(m1[i], tm1[i]);
                cf1[i] = exp2a(m1[i] - mn1); m1[i] = mn1; ls1[i] *= cf1[i];
            }
            #pragma unroll
            for (int f = 0; f < 8; ++f) { o0[f] *= cf0; o1[f] *= cf1; }
        }
        #pragma unroll
        for (int tt = 0; tt < 4; ++tt)
            #pragma unroll
            for (int i = 0; i < 4; ++i) {
                float p0 = exp2a(s0[tt][i] - m0[i]);
                ls0[i] += p0;
                P[w][lg*4 + i][tt*16 + lr] = (f16)p0;
                float p1 = exp2a(s1[tt][i] - m1[i]);
                ls1[i] += p1;
                P[w][16 + lg*4 + i][tt*16 + lr] = (f16)p1;
            }
        asm volatile("s_waitcnt lgkmcnt(0)" ::: "memory");
        __builtin_amdgcn_sched_barrier(0);

        // ---- PV: 16 shared V-frag loads, 32 MFMAs ----
        #pragma unroll
        for (int kw = 0; kw < 2; ++kw) {
            f16x8 pa0 = *(const f16x8*)&P[w][lr][kw*32 + lg*8];
            f16x8 pa1 = *(const f16x8*)&P[w][16 + lr][kw*32 + lg*8];
            #pragma unroll
            for (int f = 0; f < 8; ++f) {
                f16x8 vb = ld8((const f16*)(Vc + (f*16 + lr)*128 + voff[kw]));
                o0[f] = MFMA16(pa0, vb, o0[f]);
                o1[f] = MFMA16(pa1, vb, o1[f]);
            }
        }
        asm volatile("s_waitcnt vmcnt(0)" ::: "memory");
        __syncthreads();
    }

    #pragma unroll
    for (int i = 0; i < 4; ++i) {
        float a = ls0[i];
        a += __shfl_xor(a, 1); a += __shfl_xor(a, 2); a += __shfl_xor(a, 4); a += __shfl_xor(a, 8);
        float inv0 = 1.0f / a;
        float b = ls1[i];
        b += __shfl_xor(b, 1); b += __shfl_xor(b, 2); b += __shfl_xor(b, 4); b += __shfl_xor(b, 8);
        float inv1 = 1.0f / b;
        #pragma unroll
        for (int f = 0; f < 8; ++f) {
            out16[(size_t)(q0 + lg*4 + i) * 2048 + h*128 + f*16 + lr]      = (f16)(o0[f][i] * inv0);
            out16[(size_t)(q0 + 16 + lg*4 + i) * 2048 + h*128 + f*16 + lr] = (f16)(o1[f][i] * inv1);
        }
    }
    #undef STAGE
}

extern "C" void kernel_launch(void* const* d_in, const int* in_sizes, int n_in,
                              void* d_out, int out_size, void* d_ws, size_t ws_size,
                              hipStream_t stream) {
    const float* h     = (const float*)d_in[0];
    const float* wq    = (const float*)d_in[1];
    const float* wk    = (const float*)d_in[2];
    const float* wv    = (const float*)d_in[3];
    const float* wo    = (const float*)d_in[4];
    const float* qnw   = (const float*)d_in[5];
    const float* knw   = (const float*)d_in[6];
    const float* sw1   = (const float*)d_in[7];
    const float* sb1   = (const float*)d_in[8];
    const float* sw2   = (const float*)d_in[9];
    const float* sb2   = (const float*)d_in[10];
    const float* sscal = (const float*)d_in[11];
    const float* ka    = (const float*)d_in[12];
    const float* kb    = (const float*)d_in[13];
    const float* cosb  = (const float*)d_in[14];
    const float* sinb  = (const float*)d_in[15];
    float* outp = (float*)d_out;

    char* ws = (char*)d_ws;
    size_t off = 0;
    f16*    h16    = (f16*)(ws + off);   off += (size_t)4096*2048*2;
    f16*    wqkvt  = (f16*)(ws + off);   off += (size_t)3072*2048*2;
    f16*    wot    = (f16*)(ws + off);   off += (size_t)2048*2048*2;
    float*  qkvraw = (float*)(ws + off); off += (size_t)4096*3072*4;
    f16*    qr     = (f16*)(ws + off);   off += (size_t)4096*2048*2;
    float*  kn     = (float*)(ws + off); off += (size_t)4096*512*4;
    f16*    attn16 = (f16*)(ws + off);   off += (size_t)4096*2048*2;
    float*  T      = (float*)(ws + off); off += (size_t)2*32*16*512*4;
    f16*    Kf     = (f16*)(ws + off);   off += (size_t)4*2688*128*2;
    f16*    VfT    = (f16*)(ws + off);   off += (size_t)4*128*2688*2;
    double* logitsD= (double*)(ws + off);off += (size_t)4096*8;
    float*  iw     = (float*)(ws + off); off += (size_t)4096*4;
    int*    sel    = (int*)(ws + off);   off += (size_t)2048*4;

    k_cvt<<<4096, 256, 0, stream>>>(h, h16);
    k_transpose<<<dim3(64,64), dim3(32,8), 0, stream>>>(wq, wqkvt, 2048, 0);
    k_transpose<<<dim3(16,64), dim3(32,8), 0, stream>>>(wk, wqkvt, 512, 2048);
    k_transpose<<<dim3(16,64), dim3(32,8), 0, stream>>>(wv, wqkvt, 512, 2560);
    k_transpose<<<dim3(64,64), dim3(32,8), 0, stream>>>(wo, wot, 2048, 0);
    k_mlp<<<1024, 256, 0, stream>>>(h, sw1, sb1, sw2, sb2, logitsD, iw);
    k_topk<<<1, 1024, 0, stream>>>(logitsD, sel);
    k_gemm<<<dim3(24,32), 256, 0, stream>>>(h16, wqkvt, qkvraw, 4096, 3072, 2048);
    k_normq<<<4096, 256, 0, stream>>>(qkvraw, qnw, cosb, sinb, qr);
    k_normk<<<4096, 64, 0, stream>>>(qkvraw, knw, kn);
    k_gather<<<2048, 128, 0, stream>>>(sel, kn, qkvraw, cosb, sinb, Kf, VfT);
    k_sketch1<<<dim3(512,2), 256, 0, stream>>>(kn, qkvraw, iw, kb, T);
    k_sketch2<<<dim3(640,2), 256, 0, stream>>>(T, ka, sscal, Kf, VfT);
    k_attn<<<dim3(16,16), 512, 0, stream>>>(qr, Kf, VfT, attn16);
    k_gemm<<<dim3(16,32), 256, 0, stream>>>(attn16, wot, outp, 4096, 2048, 2048);
}

// Round 4
// 461.272 us; speedup vs baseline: 2.2555x; 1.1490x over previous
//
#include <hip/hip_runtime.h>
#include <math.h>

typedef _Float16 f16;
typedef f16 f16x8 __attribute__((ext_vector_type(8)));
typedef float f32x4 __attribute__((ext_vector_type(4)));

#define MFMA16(a,b,c) __builtin_amdgcn_mfma_f32_16x16x32_f16(a,b,c,0,0,0)

static __device__ __forceinline__ f16x8 ld8(const f16* p) { return *(const f16x8*)p; }

static __device__ __forceinline__ float exp2a(float x) {
    float r; asm("v_exp_f32 %0, %1" : "=v"(r) : "v"(x)); return r;
}

#if __has_builtin(__builtin_amdgcn_global_load_lds)
#define GLL16(g, lptr) __builtin_amdgcn_global_load_lds((const __attribute__((address_space(1))) void*)(g), (__attribute__((address_space(3))) void*)(lptr), 16, 0, 0)
#else
#define GLL16(g, lptr) do { *(int4*)(lptr) = *(const int4*)(g); } while (0)
#endif

// ---------------- f32 -> f16 convert (8 elems/thread) ----------------
__global__ __launch_bounds__(256) void k_cvt(const float* __restrict__ in, f16* __restrict__ out) {
    int idx = blockIdx.x * 256 + threadIdx.x;
    int base = idx * 8;
    float4 a = *(const float4*)&in[base];
    float4 b = *(const float4*)&in[base + 4];
    f16x8 v;
    v[0]=(f16)a.x; v[1]=(f16)a.y; v[2]=(f16)a.z; v[3]=(f16)a.w;
    v[4]=(f16)b.x; v[5]=(f16)b.y; v[6]=(f16)b.z; v[7]=(f16)b.w;
    *(f16x8*)&out[base] = v;
}

// ---------------- transpose f32 [K=2048][inCols] -> f16 [inCols][2048] ----------------
__global__ __launch_bounds__(256) void k_transpose(const float* __restrict__ in, f16* __restrict__ out,
                                                   int inCols, int rowOff) {
    __shared__ float tile[32][33];
    int tx = threadIdx.x, ty = threadIdx.y;
    int x = blockIdx.x * 32 + tx;
    int y0 = blockIdx.y * 32;
    #pragma unroll
    for (int i = 0; i < 4; ++i)
        tile[ty + i*8][tx] = in[(size_t)(y0 + ty + i*8) * inCols + x];
    __syncthreads();
    #pragma unroll
    for (int i = 0; i < 4; ++i)
        out[(size_t)(rowOff + blockIdx.x*32 + ty + i*8) * 2048 + y0 + tx] = (f16)tile[tx][ty + i*8];
}

// ---------------- gating MLP in f64: logits + iw ----------------
__global__ __launch_bounds__(256) void k_mlp(const float* __restrict__ h, const float* __restrict__ w1,
                                             const float* __restrict__ b1, const float* __restrict__ w2,
                                             const float* __restrict__ b2, double* __restrict__ logitsD,
                                             float* __restrict__ iw) {
    __shared__ float hl[4 * 2048];
    __shared__ double tl[4][64];
    int tid = threadIdx.x;
    int s0 = blockIdx.x * 4;
    #pragma unroll
    for (int p = 0; p < 8; ++p) {
        int off = p * 1024 + tid * 4;
        *(float4*)&hl[off] = *(const float4*)&h[(size_t)s0 * 2048 + off];
    }
    __syncthreads();
    int j = tid & 63, r = tid >> 6;
    const float* hr = &hl[r * 2048];
    double acc = 0.0;
    for (int c = 0; c < 2048; ++c) acc += (double)hr[c] * (double)w1[c * 64 + j];
    acc += (double)b1[j];
    tl[r][j] = tanh(acc);
    __syncthreads();
    int lane = tid & 63, rr = tid >> 6;
    double v = tl[rr][lane] * (double)w2[lane];
    for (int o = 32; o > 0; o >>= 1) v += __shfl_down(v, o);
    if (lane == 0) {
        double lg = v + (double)b2[0] - 1.8562979903656263; // log(4096/640)
        logitsD[s0 + rr] = lg;
        iw[s0 + rr] = (float)(1.0 / (1.0 + exp(-lg)));
    }
}

// ---------------- top-2048 of 4096 via MSB radix select (order-free set) ----------------
__global__ __launch_bounds__(1024) void k_topk(const double* __restrict__ logitsD, int* __restrict__ sel) {
    __shared__ unsigned long long keys[4096];
    __shared__ unsigned int hist[2048];
    __shared__ unsigned int bcast[2];
    __shared__ unsigned int cA, cB;
    int tid = threadIdx.x;
    for (int i = tid; i < 4096; i += 1024) {
        unsigned long long u = (unsigned long long)__double_as_longlong(logitsD[i]);
        keys[i] = (u >> 63) ? ~u : (u | 0x8000000000000000ull); // monotonic map
    }
    if (tid == 0) { cA = 0; cB = 0; }
    unsigned long long Tpart = 0;
    unsigned int need = 2048;
    #pragma unroll 1
    for (int lvl = 0; lvl < 6; ++lvl) {
        int shift = (lvl < 5) ? (53 - 11*lvl) : 0;
        int width = (lvl < 5) ? 11 : 9;
        unsigned int nb = 1u << width;
        int hiShift = shift + width;
        for (int i = tid; i < (int)nb; i += 1024) hist[i] = 0;
        __syncthreads();
        for (int i = tid; i < 4096; i += 1024) {
            unsigned long long k = keys[i];
            bool cand = (lvl == 0) || ((k >> hiShift) == (Tpart >> hiShift));
            if (cand) atomicAdd(&hist[(unsigned int)(k >> shift) & (nb - 1u)], 1u);
        }
        __syncthreads();
        if (tid < 64) {
            int chunk = (int)nb >> 6;
            int base = (int)nb - (tid + 1) * chunk;  // lane 0 owns the TOP chunk
            unsigned int sum = 0;
            for (int j = 0; j < chunk; ++j) sum += hist[base + j];
            unsigned int pre = sum;
            #pragma unroll
            for (int o = 1; o < 64; o <<= 1) {
                unsigned int t = __shfl_up(pre, o);
                if (tid >= o) pre += t;
            }
            unsigned int preEx = pre - sum;
            if (preEx < need && need <= pre) {
                unsigned int cum = preEx;
                for (int j = chunk - 1; j >= 0; --j) {
                    unsigned int c = hist[base + j];
                    if (cum + c >= need) { bcast[0] = (unsigned int)(base + j); bcast[1] = need - cum; break; }
                    cum += c;
                }
            }
        }
        __syncthreads();
        Tpart |= ((unsigned long long)bcast[0]) << shift;
        need = bcast[1];
        __syncthreads();
    }
    // Tpart = exact 2048th-largest key; need = count of ==T keys to include
    unsigned int G = 2048 - need;
    for (int i = tid; i < 4096; i += 1024) {
        unsigned long long k = keys[i];
        if (k > Tpart) { unsigned int p = atomicAdd(&cA, 1u); sel[p] = i; }
        else if (k == Tpart) { unsigned int q = atomicAdd(&cB, 1u); if (q < need) sel[G + q] = i; }
    }
}

// ---------------- f16 GEMM: C[M][N] = A[M][K] * Bt[N][K]^T, f32 out ----------------
__global__ __launch_bounds__(256) void k_gemm(const f16* __restrict__ A, const f16* __restrict__ Bt,
                                              float* __restrict__ C, int M, int N, int K) {
    __shared__ f16 As[128 * 32];
    __shared__ f16 Bs[128 * 32];
    int tid = threadIdx.x;
    int w = tid >> 6, l = tid & 63, lr = l & 15, lg = l >> 4;
    int wr = w >> 1, wc = w & 1;
    int row0 = blockIdx.y * 128, col0 = blockIdx.x * 128;
    f32x4 zero = {0.f, 0.f, 0.f, 0.f};
    f32x4 acc[4][4];
    #pragma unroll
    for (int m = 0; m < 4; ++m)
        #pragma unroll
        for (int n = 0; n < 4; ++n) acc[m][n] = zero;
    for (int k0 = 0; k0 < K; k0 += 32) {
        #pragma unroll
        for (int p = 0; p < 2; ++p) {
            int id = p * 256 + tid;
            int r = id >> 2, c8 = (id & 3) * 8;
            GLL16(&A[(size_t)(row0 + r) * K + k0 + c8], &As[id * 8]);
            GLL16(&Bt[(size_t)(col0 + r) * K + k0 + c8], &Bs[id * 8]);
        }
        __syncthreads();
        f16x8 a[4], b[4];
        #pragma unroll
        for (int m = 0; m < 4; ++m) a[m] = ld8(&As[(wr*64 + m*16 + lr) * 32 + lg*8]);
        #pragma unroll
        for (int n = 0; n < 4; ++n) b[n] = ld8(&Bs[(wc*64 + n*16 + lr) * 32 + lg*8]);
        #pragma unroll
        for (int m = 0; m < 4; ++m)
            #pragma unroll
            for (int n = 0; n < 4; ++n)
                acc[m][n] = MFMA16(a[m], b[n], acc[m][n]);
        __syncthreads();
    }
    #pragma unroll
    for (int m = 0; m < 4; ++m)
        #pragma unroll
        for (int n = 0; n < 4; ++n)
            #pragma unroll
            for (int i = 0; i < 4; ++i)
                C[(size_t)(row0 + wr*64 + m*16 + lg*4 + i) * N + col0 + wc*64 + n*16 + lr] = acc[m][n][i];
}

// ---------------- q: RMSnorm + RoPE + fold log2(e)/sqrt(128), f16 out ----------------
__global__ __launch_bounds__(256) void k_normq(const float* __restrict__ qkv, const float* __restrict__ qnw,
                                               const float* __restrict__ cosb, const float* __restrict__ sinb,
                                               f16* __restrict__ qr) {
    int s = blockIdx.x;
    int tid = threadIdx.x;
    int h = tid >> 4, ln = tid & 15, d0 = ln * 8;
    const float* src = &qkv[(size_t)s * 3072 + h * 128 + d0];
    float4 a = *(const float4*)src, b = *(const float4*)(src + 4);
    float x[8] = {a.x,a.y,a.z,a.w,b.x,b.y,b.z,b.w};
    float ss = 0;
    #pragma unroll
    for (int j = 0; j < 8; ++j) ss += x[j]*x[j];
    ss += __shfl_xor(ss,1); ss += __shfl_xor(ss,2); ss += __shfl_xor(ss,4); ss += __shfl_xor(ss,8);
    float rn = rsqrtf(ss * (1.0f/128.0f) + 1e-6f);
    float xn[8];
    #pragma unroll
    for (int j = 0; j < 8; ++j) xn[j] = x[j] * rn * qnw[d0 + j];
    const float scl = 0.088388347648318447f * 1.4426950408889634f; // log2(e)/sqrt(128)
    f16x8 o;
    #pragma unroll
    for (int j = 0; j < 8; ++j) {
        float pr = __shfl_xor(xn[j], 8);
        float rot = (ln < 8) ? -pr : pr;
        int d = d0 + j;
        o[j] = (f16)((xn[j]*cosb[s*128 + d] + rot*sinb[s*128 + d]) * scl);
    }
    *(f16x8*)&qr[(size_t)s * 2048 + h * 128 + d0] = o;
}

// ---------------- k: RMSnorm, f32 out ----------------
__global__ __launch_bounds__(64) void k_normk(const float* __restrict__ qkv, const float* __restrict__ knw,
                                              float* __restrict__ kn) {
    int s = blockIdx.x;
    int tid = threadIdx.x;
    int h = tid >> 4, ln = tid & 15, d0 = ln * 8;
    const float* src = &qkv[(size_t)s * 3072 + 2048 + h * 128 + d0];
    float4 a = *(const float4*)src, b = *(const float4*)(src + 4);
    float x[8] = {a.x,a.y,a.z,a.w,b.x,b.y,b.z,b.w};
    float ss = 0;
    #pragma unroll
    for (int j = 0; j < 8; ++j) ss += x[j]*x[j];
    ss += __shfl_xor(ss,1); ss += __shfl_xor(ss,2); ss += __shfl_xor(ss,4); ss += __shfl_xor(ss,8);
    float rn = rsqrtf(ss * (1.0f/128.0f) + 1e-6f);
    float o[8];
    #pragma unroll
    for (int j = 0; j < 8; ++j) o[j] = x[j] * rn * knw[d0 + j];
    float* dst = &kn[(size_t)s*512 + h*128 + d0];
    *(float4*)dst = make_float4(o[0],o[1],o[2],o[3]);
    *(float4*)(dst+4) = make_float4(o[4],o[5],o[6],o[7]);
}

// ---------------- gather detail keys (rope) + values ----------------
__global__ __launch_bounds__(128) void k_gather(const int* __restrict__ sel, const float* __restrict__ kn,
                                                const float* __restrict__ qkv, const float* __restrict__ cosb,
                                                const float* __restrict__ sinb, f16* __restrict__ Kf,
                                                f16* __restrict__ VfT) {
    int j = blockIdx.x;
    int s = sel[j];
    int t = threadIdx.x; // 0..127
    float c = cosb[s*128 + t], sn = sinb[s*128 + t];
    #pragma unroll
    for (int h = 0; h < 4; ++h) {
        float x  = kn[(size_t)s*512 + h*128 + t];
        float pr = kn[(size_t)s*512 + h*128 + (t ^ 64)];
        float rot = (t < 64) ? -pr : pr;
        Kf[(size_t)(h*2688 + j) * 128 + t] = (f16)(x*c + rot*sn);
        float v = qkv[(size_t)s*3072 + 2560 + h*128 + t];
        VfT[(size_t)h*128*2688 + (size_t)t*2688 + j] = (f16)v;
    }
}

// ---------------- sketch stage 1 ----------------
__global__ __launch_bounds__(256) void k_sketch1(const float* __restrict__ kn, const float* __restrict__ qkv,
                                                 const float* __restrict__ iw, const float* __restrict__ kronb,
                                                 float* __restrict__ T) {
    int mb = blockIdx.x & 31, sa = blockIdx.x >> 5;
    int which = blockIdx.y;
    int c0 = threadIdx.x * 2;
    float a0 = 0, a1 = 0;
    for (int sb = 0; sb < 256; ++sb) {
        int s = sa * 256 + sb;
        float wgt = kronb[mb * 256 + sb] * iw[s];
        const float* src = which ? &qkv[(size_t)s*3072 + 2560] : &kn[(size_t)s*512];
        a0 += wgt * src[c0];
        a1 += wgt * src[c0 + 1];
    }
    float* dst = &T[(size_t)((which*32 + mb)*16 + sa) * 512 + c0];
    dst[0] = a0; dst[1] = a1;
}

// ---------------- sketch stage 2 ----------------
__global__ __launch_bounds__(256) void k_sketch2(const float* __restrict__ T, const float* __restrict__ krona,
                                                 const float* __restrict__ sscale, f16* __restrict__ Kf,
                                                 f16* __restrict__ VfT) {
    int m = blockIdx.x;
    int which = blockIdx.y;
    int ma = m >> 5, mb = m & 31;
    int c0 = threadIdx.x * 2;
    float sc = sscale[0];
    float a0 = 0, a1 = 0;
    #pragma unroll
    for (int sa = 0; sa < 16; ++sa) {
        float ka = krona[ma * 128 + sa];
        const float* t = &T[(size_t)((which*32 + mb)*16 + sa) * 512 + c0];
        a0 += ka * t[0];
        a1 += ka * t[1];
    }
    a0 *= sc; a1 *= sc;
    int key = 2048 + m;
    int h0 = c0 >> 7, d = c0 & 127;
    if (which == 0) {
        Kf[(size_t)(h0*2688 + key)*128 + d]     = (f16)a0;
        Kf[(size_t)(h0*2688 + key)*128 + d + 1] = (f16)a1;
    } else {
        VfT[(size_t)h0*128*2688 + (size_t)d*2688 + key]       = (f16)a0;
        VfT[(size_t)h0*128*2688 + (size_t)(d+1)*2688 + key]   = (f16)a1;
    }
}

// ---------------- flash attention v4: 4 waves x 32 q-rows, 80KB LDS, 2 blocks/CU ----------------
// KT[64][128] swz bcol^=(row&7)<<5; VT[128][64] swz bcol^=(d&7)<<4; P[4][32][64] swz byte^=(row&7)<<4.
__global__ __launch_bounds__(256, 2) void k_attn(const f16* __restrict__ qr, const f16* __restrict__ Kf,
                                                 const f16* __restrict__ VfT, f16* __restrict__ out16) {
    __shared__ f16 KT[2][64 * 128];
    __shared__ f16 VT[2][128 * 64];
    __shared__ f16 P[4][32 * 64];
    int qt = blockIdx.x, h = blockIdx.y;
    int kvh = h >> 2;
    int tid = threadIdx.x;
    int w = tid >> 6, l = tid & 63, lr = l & 15, lg = l >> 4;
    int q0 = qt * 128 + w * 32;
    const char* Kb = (const char*)(Kf + (size_t)kvh * 2688 * 128);
    const char* Vb = (const char*)(VfT + (size_t)kvh * 128 * 2688);
    char* Pw = (char*)&P[w][0];

    int koff[4], voff[2];
    #pragma unroll
    for (int c = 0; c < 4; ++c) koff[c] = (c*64 + lg*16) ^ ((lr & 7) << 5);
    #pragma unroll
    for (int kw = 0; kw < 2; ++kw) voff[kw] = (kw*64 + lg*16) ^ ((lr & 7) << 4);
    int psw = (lr & 7) << 4;   // P read swizzle (row=lr or 16+lr, same &7)

    int L0 = tid * 16;

    f16x8 aq[2][4];
    #pragma unroll
    for (int hh = 0; hh < 2; ++hh)
        #pragma unroll
        for (int c = 0; c < 4; ++c)
            aq[hh][c] = ld8(&qr[(size_t)(q0 + hh*16 + lr) * 2048 + h*128 + c*32 + lg*8]);

    f32x4 zero = {0.f,0.f,0.f,0.f};
    f32x4 o0[8], o1[8];
    #pragma unroll
    for (int f = 0; f < 8; ++f) { o0[f] = zero; o1[f] = zero; }
    float m0[4], m1[4], ls0[4], ls1[4];
    #pragma unroll
    for (int i = 0; i < 4; ++i) { m0[i] = -1e30f; m1[i] = -1e30f; ls0[i] = 0.f; ls1[i] = 0.f; }

    // stage 16KB K + 16KB V: 4 GLL16 each per thread; linear LDS dest, inv-swz global src
    #define STAGE(buf, kt)  do {                                                          \
        _Pragma("unroll")                                                                  \
        for (int i_ = 0; i_ < 4; ++i_) {                                                   \
            int L = L0 + i_*4096;                                                          \
            int krow = L >> 8, kbc = L & 255;                                              \
            GLL16(Kb + (size_t)((kt) + krow)*256 + (kbc ^ ((krow & 7) << 5)),              \
                  (char*)&KT[buf][0] + L);                                                 \
            int vd = L >> 7, vbc = L & 127;                                                \
            GLL16(Vb + (size_t)vd*5376 + (size_t)(kt)*2 + (vbc ^ ((vd & 7) << 4)),         \
                  (char*)&VT[buf][0] + L);                                                 \
        }                                                                                  \
    } while (0)

    STAGE(0, 0);
    asm volatile("s_waitcnt vmcnt(0)" ::: "memory");
    __syncthreads();

    for (int t = 0; t < 42; ++t) {
        int cur = t & 1;
        if (t < 41) STAGE(cur ^ 1, (t + 1) * 64);
        const char* Kc = (const char*)&KT[cur][0];
        const char* Vc = (const char*)&VT[cur][0];

        f32x4 s0[4], s1[4];
        #pragma unroll
        for (int tt = 0; tt < 4; ++tt) { s0[tt] = zero; s1[tt] = zero; }
        __builtin_amdgcn_s_setprio(1);
        #pragma unroll
        for (int tt = 0; tt < 4; ++tt) {
            #pragma unroll
            for (int c = 0; c < 4; ++c) {
                f16x8 kb = ld8((const f16*)(Kc + (tt*16 + lr)*256 + koff[c]));
                s0[tt] = MFMA16(aq[0][c], kb, s0[tt]);
                s1[tt] = MFMA16(aq[1][c], kb, s1[tt]);
            }
        }
        __builtin_amdgcn_s_setprio(0);

        float tm0[4], tm1[4];
        #pragma unroll
        for (int i = 0; i < 4; ++i) {
            float a = fmaxf(fmaxf(s0[0][i], s0[1][i]), fmaxf(s0[2][i], s0[3][i]));
            a = fmaxf(a, __shfl_xor(a, 1)); a = fmaxf(a, __shfl_xor(a, 2));
            a = fmaxf(a, __shfl_xor(a, 4)); a = fmaxf(a, __shfl_xor(a, 8));
            tm0[i] = a;
            float b = fmaxf(fmaxf(s1[0][i], s1[1][i]), fmaxf(s1[2][i], s1[3][i]));
            b = fmaxf(b, __shfl_xor(b, 1)); b = fmaxf(b, __shfl_xor(b, 2));
            b = fmaxf(b, __shfl_xor(b, 4)); b = fmaxf(b, __shfl_xor(b, 8));
            tm1[i] = b;
        }
        bool need = false;
        #pragma unroll
        for (int i = 0; i < 4; ++i) need = need || (tm0[i] > m0[i]+8.f) || (tm1[i] > m1[i]+8.f);
        if (__any(need)) {
            f32x4 cf0, cf1;
            #pragma unroll
            for (int i = 0; i < 4; ++i) {
                float mn0 = fmaxf(m0[i], tm0[i]);
                cf0[i] = exp2a(m0[i] - mn0); m0[i] = mn0; ls0[i] *= cf0[i];
                float mn1 = fmaxf(m1[i], tm1[i]);
                cf1[i] = exp2a(m1[i] - mn1); m1[i] = mn1; ls1[i] *= cf1[i];
            }
            #pragma unroll
            for (int f = 0; f < 8; ++f) { o0[f] *= cf0; o1[f] *= cf1; }
        }
        #pragma unroll
        for (int tt = 0; tt < 4; ++tt)
            #pragma unroll
            for (int i = 0; i < 4; ++i) {
                int r0 = lg*4 + i;
                float p0 = exp2a(s0[tt][i] - m0[i]);
                ls0[i] += p0;
                *(f16*)(Pw + ((r0*128 + (tt*16+lr)*2) ^ ((r0 & 7) << 4))) = (f16)p0;
                int r1 = 16 + r0;
                float p1 = exp2a(s1[tt][i] - m1[i]);
                ls1[i] += p1;
                *(f16*)(Pw + ((r1*128 + (tt*16+lr)*2) ^ ((r1 & 7) << 4))) = (f16)p1;
            }
        asm volatile("s_waitcnt lgkmcnt(0)" ::: "memory");
        __builtin_amdgcn_sched_barrier(0);

        __builtin_amdgcn_s_setprio(1);
        #pragma unroll
        for (int kw = 0; kw < 2; ++kw) {
            f16x8 pa0 = *(const f16x8*)(Pw + ((lr*128 + kw*64 + lg*16) ^ psw));
            f16x8 pa1 = *(const f16x8*)(Pw + (((16+lr)*128 + kw*64 + lg*16) ^ psw));
            #pragma unroll
            for (int f = 0; f < 8; ++f) {
                f16x8 vb = ld8((const f16*)(Vc + (f*16 + lr)*128 + voff[kw]));
                o0[f] = MFMA16(pa0, vb, o0[f]);
                o1[f] = MFMA16(pa1, vb, o1[f]);
            }
        }
        __builtin_amdgcn_s_setprio(0);
        asm volatile("s_waitcnt vmcnt(0)" ::: "memory");
        __syncthreads();
    }

    #pragma unroll
    for (int i = 0; i < 4; ++i) {
        float a = ls0[i];
        a += __shfl_xor(a, 1); a += __shfl_xor(a, 2); a += __shfl_xor(a, 4); a += __shfl_xor(a, 8);
        float inv0 = 1.0f / a;
        float b = ls1[i];
        b += __shfl_xor(b, 1); b += __shfl_xor(b, 2); b += __shfl_xor(b, 4); b += __shfl_xor(b, 8);
        float inv1 = 1.0f / b;
        #pragma unroll
        for (int f = 0; f < 8; ++f) {
            out16[(size_t)(q0 + lg*4 + i) * 2048 + h*128 + f*16 + lr]      = (f16)(o0[f][i] * inv0);
            out16[(size_t)(q0 + 16 + lg*4 + i) * 2048 + h*128 + f*16 + lr] = (f16)(o1[f][i] * inv1);
        }
    }
    #undef STAGE
}

extern "C" void kernel_launch(void* const* d_in, const int* in_sizes, int n_in,
                              void* d_out, int out_size, void* d_ws, size_t ws_size,
                              hipStream_t stream) {
    const float* h     = (const float*)d_in[0];
    const float* wq    = (const float*)d_in[1];
    const float* wk    = (const float*)d_in[2];
    const float* wv    = (const float*)d_in[3];
    const float* wo    = (const float*)d_in[4];
    const float* qnw   = (const float*)d_in[5];
    const float* knw   = (const float*)d_in[6];
    const float* sw1   = (const float*)d_in[7];
    const float* sb1   = (const float*)d_in[8];
    const float* sw2   = (const float*)d_in[9];
    const float* sb2   = (const float*)d_in[10];
    const float* sscal = (const float*)d_in[11];
    const float* ka    = (const float*)d_in[12];
    const float* kb    = (const float*)d_in[13];
    const float* cosb  = (const float*)d_in[14];
    const float* sinb  = (const float*)d_in[15];
    float* outp = (float*)d_out;

    char* ws = (char*)d_ws;
    size_t off = 0;
    f16*    h16    = (f16*)(ws + off);   off += (size_t)4096*2048*2;
    f16*    wqkvt  = (f16*)(ws + off);   off += (size_t)3072*2048*2;
    f16*    wot    = (f16*)(ws + off);   off += (size_t)2048*2048*2;
    float*  qkvraw = (float*)(ws + off); off += (size_t)4096*3072*4;
    f16*    qr     = (f16*)(ws + off);   off += (size_t)4096*2048*2;
    float*  kn     = (float*)(ws + off); off += (size_t)4096*512*4;
    f16*    attn16 = (f16*)(ws + off);   off += (size_t)4096*2048*2;
    float*  T      = (float*)(ws + off); off += (size_t)2*32*16*512*4;
    f16*    Kf     = (f16*)(ws + off);   off += (size_t)4*2688*128*2;
    f16*    VfT    = (f16*)(ws + off);   off += (size_t)4*128*2688*2;
    double* logitsD= (double*)(ws + off);off += (size_t)4096*8;
    float*  iw     = (float*)(ws + off); off += (size_t)4096*4;
    int*    sel    = (int*)(ws + off);   off += (size_t)2048*4;

    k_cvt<<<4096, 256, 0, stream>>>(h, h16);
    k_transpose<<<dim3(64,64), dim3(32,8), 0, stream>>>(wq, wqkvt, 2048, 0);
    k_transpose<<<dim3(16,64), dim3(32,8), 0, stream>>>(wk, wqkvt, 512, 2048);
    k_transpose<<<dim3(16,64), dim3(32,8), 0, stream>>>(wv, wqkvt, 512, 2560);
    k_transpose<<<dim3(64,64), dim3(32,8), 0, stream>>>(wo, wot, 2048, 0);
    k_mlp<<<1024, 256, 0, stream>>>(h, sw1, sb1, sw2, sb2, logitsD, iw);
    k_topk<<<1, 1024, 0, stream>>>(logitsD, sel);
    k_gemm<<<dim3(24,32), 256, 0, stream>>>(h16, wqkvt, qkvraw, 4096, 3072, 2048);
    k_normq<<<4096, 256, 0, stream>>>(qkvraw, qnw, cosb, sinb, qr);
    k_normk<<<4096, 64, 0, stream>>>(qkvraw, knw, kn);
    k_gather<<<2048, 128, 0, stream>>>(sel, kn, qkvraw, cosb, sinb, Kf, VfT);
    k_sketch1<<<dim3(512,2), 256, 0, stream>>>(kn, qkvraw, iw, kb, T);
    k_sketch2<<<dim3(640,2), 256, 0, stream>>>(T, ka, sscal, Kf, VfT);
    k_attn<<<dim3(32,16), 256, 0, stream>>>(qr, Kf, VfT, attn16);
    k_gemm<<<dim3(16,32), 256, 0, stream>>>(attn16, wot, outp, 4096, 2048, 2048);
}

// Round 5
// 432.211 us; speedup vs baseline: 2.4071x; 1.0672x over previous
//
#include <hip/hip_runtime.h>
#include <math.h>

typedef _Float16 f16;
typedef f16 f16x8 __attribute__((ext_vector_type(8)));
typedef float f32x4 __attribute__((ext_vector_type(4)));

#define MFMA16(a,b,c) __builtin_amdgcn_mfma_f32_16x16x32_f16(a,b,c,0,0,0)

static __device__ __forceinline__ f16x8 ld8(const f16* p) { return *(const f16x8*)p; }

static __device__ __forceinline__ float exp2a(float x) {
    float r; asm("v_exp_f32 %0, %1" : "=v"(r) : "v"(x)); return r;
}

#if __has_builtin(__builtin_amdgcn_global_load_lds)
#define GLL16(g, lptr) __builtin_amdgcn_global_load_lds((const __attribute__((address_space(1))) void*)(g), (__attribute__((address_space(3))) void*)(lptr), 16, 0, 0)
#else
#define GLL16(g, lptr) do { *(int4*)(lptr) = *(const int4*)(g); } while (0)
#endif

// ---------------- gating MLP in f64 (+ fused h->f16 convert) ----------------
__global__ __launch_bounds__(256) void k_mlp(const float* __restrict__ h, const float* __restrict__ w1,
                                             const float* __restrict__ b1, const float* __restrict__ w2,
                                             const float* __restrict__ b2, double* __restrict__ logitsD,
                                             float* __restrict__ iw, f16* __restrict__ h16) {
    __shared__ float hl[4 * 2048];
    __shared__ double tl[4][64];
    int tid = threadIdx.x;
    int s0 = blockIdx.x * 4;
    #pragma unroll
    for (int p = 0; p < 8; ++p) {
        int off = p * 1024 + tid * 4;
        *(float4*)&hl[off] = *(const float4*)&h[(size_t)s0 * 2048 + off];
    }
    __syncthreads();
    // fused convert: write h16 for these 4 rows
    #pragma unroll
    for (int p = 0; p < 4; ++p) {
        int off = p * 2048 + tid * 8;
        f16x8 v;
        #pragma unroll
        for (int j = 0; j < 8; ++j) v[j] = (f16)hl[off + j];
        *(f16x8*)&h16[(size_t)s0 * 2048 + off] = v;
    }
    int j = tid & 63, r = tid >> 6;
    const float* hr = &hl[r * 2048];
    double acc = 0.0;
    for (int c = 0; c < 2048; ++c) acc += (double)hr[c] * (double)w1[c * 64 + j];
    acc += (double)b1[j];
    tl[r][j] = tanh(acc);
    __syncthreads();
    int lane = tid & 63, rr = tid >> 6;
    double v = tl[rr][lane] * (double)w2[lane];
    for (int o = 32; o > 0; o >>= 1) v += __shfl_down(v, o);
    if (lane == 0) {
        double lg = v + (double)b2[0] - 1.8562979903656263; // log(4096/640)
        logitsD[s0 + rr] = lg;
        iw[s0 + rr] = (float)(1.0 / (1.0 + exp(-lg)));
    }
}

// ---------------- merged weight transposes: wq|wk|wv -> wqkvt [3072][2048] f16 ----------------
__global__ __launch_bounds__(256) void k_transpose_qkv(const float* __restrict__ wq, const float* __restrict__ wk,
                                                       const float* __restrict__ wv, f16* __restrict__ out) {
    __shared__ float tile[32][33];
    int bx = blockIdx.x;
    const float* in; int inCols, colBase, rowOff;
    if (bx < 64)      { in = wq; inCols = 2048; colBase = bx * 32;        rowOff = colBase; }
    else if (bx < 80) { in = wk; inCols = 512;  colBase = (bx - 64) * 32; rowOff = 2048 + colBase; }
    else              { in = wv; inCols = 512;  colBase = (bx - 80) * 32; rowOff = 2560 + colBase; }
    int tx = threadIdx.x, ty = threadIdx.y;
    int x = colBase + tx;
    int y0 = blockIdx.y * 32;
    #pragma unroll
    for (int i = 0; i < 4; ++i)
        tile[ty + i*8][tx] = in[(size_t)(y0 + ty + i*8) * inCols + x];
    __syncthreads();
    #pragma unroll
    for (int i = 0; i < 4; ++i)
        out[(size_t)(rowOff + ty + i*8) * 2048 + y0 + tx] = (f16)tile[tx][ty + i*8];
}

// ---------------- transpose f32 [2048][2048] -> f16 [2048][2048] (wo) ----------------
__global__ __launch_bounds__(256) void k_transpose(const float* __restrict__ in, f16* __restrict__ out,
                                                   int inCols, int rowOff) {
    __shared__ float tile[32][33];
    int tx = threadIdx.x, ty = threadIdx.y;
    int x = blockIdx.x * 32 + tx;
    int y0 = blockIdx.y * 32;
    #pragma unroll
    for (int i = 0; i < 4; ++i)
        tile[ty + i*8][tx] = in[(size_t)(y0 + ty + i*8) * inCols + x];
    __syncthreads();
    #pragma unroll
    for (int i = 0; i < 4; ++i)
        out[(size_t)(rowOff + blockIdx.x*32 + ty + i*8) * 2048 + y0 + tx] = (f16)tile[tx][ty + i*8];
}

// ---------------- top-2048 of 4096 via MSB radix select (order-free set) ----------------
__global__ __launch_bounds__(1024) void k_topk(const double* __restrict__ logitsD, int* __restrict__ sel) {
    __shared__ unsigned long long keys[4096];
    __shared__ unsigned int hist[2048];
    __shared__ unsigned int bcast[2];
    __shared__ unsigned int cA, cB;
    int tid = threadIdx.x;
    for (int i = tid; i < 4096; i += 1024) {
        unsigned long long u = (unsigned long long)__double_as_longlong(logitsD[i]);
        keys[i] = (u >> 63) ? ~u : (u | 0x8000000000000000ull); // monotonic map
    }
    if (tid == 0) { cA = 0; cB = 0; }
    unsigned long long Tpart = 0;
    unsigned int need = 2048;
    #pragma unroll 1
    for (int lvl = 0; lvl < 6; ++lvl) {
        int shift = (lvl < 5) ? (53 - 11*lvl) : 0;
        int width = (lvl < 5) ? 11 : 9;
        unsigned int nb = 1u << width;
        int hiShift = shift + width;
        for (int i = tid; i < (int)nb; i += 1024) hist[i] = 0;
        __syncthreads();
        for (int i = tid; i < 4096; i += 1024) {
            unsigned long long k = keys[i];
            bool cand = (lvl == 0) || ((k >> hiShift) == (Tpart >> hiShift));
            if (cand) atomicAdd(&hist[(unsigned int)(k >> shift) & (nb - 1u)], 1u);
        }
        __syncthreads();
        if (tid < 64) {
            int chunk = (int)nb >> 6;
            int base = (int)nb - (tid + 1) * chunk;  // lane 0 owns the TOP chunk
            unsigned int sum = 0;
            for (int j = 0; j < chunk; ++j) sum += hist[base + j];
            unsigned int pre = sum;
            #pragma unroll
            for (int o = 1; o < 64; o <<= 1) {
                unsigned int t = __shfl_up(pre, o);
                if (tid >= o) pre += t;
            }
            unsigned int preEx = pre - sum;
            if (preEx < need && need <= pre) {
                unsigned int cum = preEx;
                for (int j = chunk - 1; j >= 0; --j) {
                    unsigned int c = hist[base + j];
                    if (cum + c >= need) { bcast[0] = (unsigned int)(base + j); bcast[1] = need - cum; break; }
                    cum += c;
                }
            }
        }
        __syncthreads();
        Tpart |= ((unsigned long long)bcast[0]) << shift;
        need = bcast[1];
        __syncthreads();
    }
    unsigned int G = 2048 - need;
    for (int i = tid; i < 4096; i += 1024) {
        unsigned long long k = keys[i];
        if (k > Tpart) { unsigned int p = atomicAdd(&cA, 1u); sel[p] = i; }
        else if (k == Tpart) { unsigned int q = atomicAdd(&cB, 1u); if (q < need) sel[G + q] = i; }
    }
}

// ---------------- f16 GEMM: C[M][N] = A[M][K] * Bt[N][K]^T, f32 out ----------------
__global__ __launch_bounds__(256) void k_gemm(const f16* __restrict__ A, const f16* __restrict__ Bt,
                                              float* __restrict__ C, int M, int N, int K) {
    __shared__ f16 As[128 * 32];
    __shared__ f16 Bs[128 * 32];
    int tid = threadIdx.x;
    int w = tid >> 6, l = tid & 63, lr = l & 15, lg = l >> 4;
    int wr = w >> 1, wc = w & 1;
    int row0 = blockIdx.y * 128, col0 = blockIdx.x * 128;
    f32x4 zero = {0.f, 0.f, 0.f, 0.f};
    f32x4 acc[4][4];
    #pragma unroll
    for (int m = 0; m < 4; ++m)
        #pragma unroll
        for (int n = 0; n < 4; ++n) acc[m][n] = zero;
    for (int k0 = 0; k0 < K; k0 += 32) {
        #pragma unroll
        for (int p = 0; p < 2; ++p) {
            int id = p * 256 + tid;
            int r = id >> 2, c8 = (id & 3) * 8;
            GLL16(&A[(size_t)(row0 + r) * K + k0 + c8], &As[id * 8]);
            GLL16(&Bt[(size_t)(col0 + r) * K + k0 + c8], &Bs[id * 8]);
        }
        __syncthreads();
        f16x8 a[4], b[4];
        #pragma unroll
        for (int m = 0; m < 4; ++m) a[m] = ld8(&As[(wr*64 + m*16 + lr) * 32 + lg*8]);
        #pragma unroll
        for (int n = 0; n < 4; ++n) b[n] = ld8(&Bs[(wc*64 + n*16 + lr) * 32 + lg*8]);
        #pragma unroll
        for (int m = 0; m < 4; ++m)
            #pragma unroll
            for (int n = 0; n < 4; ++n)
                acc[m][n] = MFMA16(a[m], b[n], acc[m][n]);
        __syncthreads();
    }
    #pragma unroll
    for (int m = 0; m < 4; ++m)
        #pragma unroll
        for (int n = 0; n < 4; ++n)
            #pragma unroll
            for (int i = 0; i < 4; ++i)
                C[(size_t)(row0 + wr*64 + m*16 + lg*4 + i) * N + col0 + wc*64 + n*16 + lr] = acc[m][n][i];
}

// ---------------- fused q-norm+RoPE (waves 0-3) and k-norm (wave 4) ----------------
__global__ __launch_bounds__(320) void k_norm(const float* __restrict__ qkv, const float* __restrict__ qnw,
                                              const float* __restrict__ knw, const float* __restrict__ cosb,
                                              const float* __restrict__ sinb, f16* __restrict__ qr,
                                              float* __restrict__ kn) {
    int s = blockIdx.x;
    int tid = threadIdx.x;
    if (tid < 256) {
        int h = tid >> 4, ln = tid & 15, d0 = ln * 8;
        const float* src = &qkv[(size_t)s * 3072 + h * 128 + d0];
        float4 a = *(const float4*)src, b = *(const float4*)(src + 4);
        float x[8] = {a.x,a.y,a.z,a.w,b.x,b.y,b.z,b.w};
        float ss = 0;
        #pragma unroll
        for (int j = 0; j < 8; ++j) ss += x[j]*x[j];
        ss += __shfl_xor(ss,1); ss += __shfl_xor(ss,2); ss += __shfl_xor(ss,4); ss += __shfl_xor(ss,8);
        float rn = rsqrtf(ss * (1.0f/128.0f) + 1e-6f);
        float xn[8];
        #pragma unroll
        for (int j = 0; j < 8; ++j) xn[j] = x[j] * rn * qnw[d0 + j];
        const float scl = 0.088388347648318447f * 1.4426950408889634f; // log2(e)/sqrt(128)
        f16x8 o;
        #pragma unroll
        for (int j = 0; j < 8; ++j) {
            float pr = __shfl_xor(xn[j], 8);
            float rot = (ln < 8) ? -pr : pr;
            int d = d0 + j;
            o[j] = (f16)((xn[j]*cosb[s*128 + d] + rot*sinb[s*128 + d]) * scl);
        }
        *(f16x8*)&qr[(size_t)s * 2048 + h * 128 + d0] = o;
    } else {
        int t2 = tid - 256;
        int h = t2 >> 4, ln = t2 & 15, d0 = ln * 8;
        const float* src = &qkv[(size_t)s * 3072 + 2048 + h * 128 + d0];
        float4 a = *(const float4*)src, b = *(const float4*)(src + 4);
        float x[8] = {a.x,a.y,a.z,a.w,b.x,b.y,b.z,b.w};
        float ss = 0;
        #pragma unroll
        for (int j = 0; j < 8; ++j) ss += x[j]*x[j];
        ss += __shfl_xor(ss,1); ss += __shfl_xor(ss,2); ss += __shfl_xor(ss,4); ss += __shfl_xor(ss,8);
        float rn = rsqrtf(ss * (1.0f/128.0f) + 1e-6f);
        float o[8];
        #pragma unroll
        for (int j = 0; j < 8; ++j) o[j] = x[j] * rn * knw[d0 + j];
        float* dst = &kn[(size_t)s*512 + h*128 + d0];
        *(float4*)dst = make_float4(o[0],o[1],o[2],o[3]);
        *(float4*)(dst+4) = make_float4(o[4],o[5],o[6],o[7]);
    }
}

// ---------------- gather detail keys (rope) + values ----------------
__global__ __launch_bounds__(128) void k_gather(const int* __restrict__ sel, const float* __restrict__ kn,
                                                const float* __restrict__ qkv, const float* __restrict__ cosb,
                                                const float* __restrict__ sinb, f16* __restrict__ Kf,
                                                f16* __restrict__ VfT) {
    int j = blockIdx.x;
    int s = sel[j];
    int t = threadIdx.x; // 0..127
    float c = cosb[s*128 + t], sn = sinb[s*128 + t];
    #pragma unroll
    for (int h = 0; h < 4; ++h) {
        float x  = kn[(size_t)s*512 + h*128 + t];
        float pr = kn[(size_t)s*512 + h*128 + (t ^ 64)];
        float rot = (t < 64) ? -pr : pr;
        Kf[(size_t)(h*2688 + j) * 128 + t] = (f16)(x*c + rot*sn);
        float v = qkv[(size_t)s*3072 + 2560 + h*128 + t];
        VfT[(size_t)h*128*2688 + (size_t)t*2688 + j] = (f16)v;
    }
}

// ---------------- sketch stage 1 ----------------
__global__ __launch_bounds__(256) void k_sketch1(const float* __restrict__ kn, const float* __restrict__ qkv,
                                                 const float* __restrict__ iw, const float* __restrict__ kronb,
                                                 float* __restrict__ T) {
    int mb = blockIdx.x & 31, sa = blockIdx.x >> 5;
    int which = blockIdx.y;
    int c0 = threadIdx.x * 2;
    float a0 = 0, a1 = 0;
    for (int sb = 0; sb < 256; ++sb) {
        int s = sa * 256 + sb;
        float wgt = kronb[mb * 256 + sb] * iw[s];
        const float* src = which ? &qkv[(size_t)s*3072 + 2560] : &kn[(size_t)s*512];
        a0 += wgt * src[c0];
        a1 += wgt * src[c0 + 1];
    }
    float* dst = &T[(size_t)((which*32 + mb)*16 + sa) * 512 + c0];
    dst[0] = a0; dst[1] = a1;
}

// ---------------- sketch stage 2 ----------------
__global__ __launch_bounds__(256) void k_sketch2(const float* __restrict__ T, const float* __restrict__ krona,
                                                 const float* __restrict__ sscale, f16* __restrict__ Kf,
                                                 f16* __restrict__ VfT) {
    int m = blockIdx.x;
    int which = blockIdx.y;
    int ma = m >> 5, mb = m & 31;
    int c0 = threadIdx.x * 2;
    float sc = sscale[0];
    float a0 = 0, a1 = 0;
    #pragma unroll
    for (int sa = 0; sa < 16; ++sa) {
        float ka = krona[ma * 128 + sa];
        const float* t = &T[(size_t)((which*32 + mb)*16 + sa) * 512 + c0];
        a0 += ka * t[0];
        a1 += ka * t[1];
    }
    a0 *= sc; a1 *= sc;
    int key = 2048 + m;
    int h0 = c0 >> 7, d = c0 & 127;
    if (which == 0) {
        Kf[(size_t)(h0*2688 + key)*128 + d]     = (f16)a0;
        Kf[(size_t)(h0*2688 + key)*128 + d + 1] = (f16)a1;
    } else {
        VfT[(size_t)h0*128*2688 + (size_t)d*2688 + key]       = (f16)a0;
        VfT[(size_t)h0*128*2688 + (size_t)(d+1)*2688 + key]   = (f16)a1;
    }
}

// ---------------- flash attention v5: local-max trigger (no shfl in common path) ----------------
__global__ __launch_bounds__(256, 2) void k_attn(const f16* __restrict__ qr, const f16* __restrict__ Kf,
                                                 const f16* __restrict__ VfT, f16* __restrict__ out16) {
    __shared__ f16 KT[2][64 * 128];
    __shared__ f16 VT[2][128 * 64];
    __shared__ f16 P[4][32 * 64];
    int qt = blockIdx.x, h = blockIdx.y;
    int kvh = h >> 2;
    int tid = threadIdx.x;
    int w = tid >> 6, l = tid & 63, lr = l & 15, lg = l >> 4;
    int q0 = qt * 128 + w * 32;
    const char* Kb = (const char*)(Kf + (size_t)kvh * 2688 * 128);
    const char* Vb = (const char*)(VfT + (size_t)kvh * 128 * 2688);
    char* Pw = (char*)&P[w][0];

    int koff[4], voff[2];
    #pragma unroll
    for (int c = 0; c < 4; ++c) koff[c] = (c*64 + lg*16) ^ ((lr & 7) << 5);
    #pragma unroll
    for (int kw = 0; kw < 2; ++kw) voff[kw] = (kw*64 + lg*16) ^ ((lr & 7) << 4);
    int psw = (lr & 7) << 4;

    int L0 = tid * 16;

    f16x8 aq[2][4];
    #pragma unroll
    for (int hh = 0; hh < 2; ++hh)
        #pragma unroll
        for (int c = 0; c < 4; ++c)
            aq[hh][c] = ld8(&qr[(size_t)(q0 + hh*16 + lr) * 2048 + h*128 + c*32 + lg*8]);

    f32x4 zero = {0.f,0.f,0.f,0.f};
    f32x4 o0[8], o1[8];
    #pragma unroll
    for (int f = 0; f < 8; ++f) { o0[f] = zero; o1[f] = zero; }
    float m0[4], m1[4], ls0[4], ls1[4];
    #pragma unroll
    for (int i = 0; i < 4; ++i) { m0[i] = -1e30f; m1[i] = -1e30f; ls0[i] = 0.f; ls1[i] = 0.f; }

    #define STAGE(buf, kt)  do {                                                          \
        _Pragma("unroll")                                                                  \
        for (int i_ = 0; i_ < 4; ++i_) {                                                   \
            int L = L0 + i_*4096;                                                          \
            int krow = L >> 8, kbc = L & 255;                                              \
            GLL16(Kb + (size_t)((kt) + krow)*256 + (kbc ^ ((krow & 7) << 5)),              \
                  (char*)&KT[buf][0] + L);                                                 \
            int vd = L >> 7, vbc = L & 127;                                                \
            GLL16(Vb + (size_t)vd*5376 + (size_t)(kt)*2 + (vbc ^ ((vd & 7) << 4)),         \
                  (char*)&VT[buf][0] + L);                                                 \
        }                                                                                  \
    } while (0)

    STAGE(0, 0);
    asm volatile("s_waitcnt vmcnt(0)" ::: "memory");
    __syncthreads();

    for (int t = 0; t < 42; ++t) {
        int cur = t & 1;
        if (t < 41) STAGE(cur ^ 1, (t + 1) * 64);
        const char* Kc = (const char*)&KT[cur][0];
        const char* Vc = (const char*)&VT[cur][0];

        f32x4 s0[4], s1[4];
        #pragma unroll
        for (int tt = 0; tt < 4; ++tt) { s0[tt] = zero; s1[tt] = zero; }
        __builtin_amdgcn_s_setprio(1);
        #pragma unroll
        for (int tt = 0; tt < 4; ++tt) {
            #pragma unroll
            for (int c = 0; c < 4; ++c) {
                f16x8 kb = ld8((const f16*)(Kc + (tt*16 + lr)*256 + koff[c]));
                s0[tt] = MFMA16(aq[0][c], kb, s0[tt]);
                s1[tt] = MFMA16(aq[1][c], kb, s1[tt]);
            }
        }
        __builtin_amdgcn_s_setprio(0);

        // in-lane local max only (each lane holds 4 keys per row: tt=0..3)
        float tl0[4], tl1[4];
        bool need = false;
        #pragma unroll
        for (int i = 0; i < 4; ++i) {
            tl0[i] = fmaxf(fmaxf(s0[0][i], s0[1][i]), fmaxf(s0[2][i], s0[3][i]));
            tl1[i] = fmaxf(fmaxf(s1[0][i], s1[1][i]), fmaxf(s1[2][i], s1[3][i]));
            need = need || (tl0[i] > m0[i]+8.f) || (tl1[i] > m1[i]+8.f);
        }
        if (__any(need)) {
            // rare path: full cross-lane row max + rescale
            f32x4 cf0, cf1;
            #pragma unroll
            for (int i = 0; i < 4; ++i) {
                float a = tl0[i];
                a = fmaxf(a, __shfl_xor(a, 1)); a = fmaxf(a, __shfl_xor(a, 2));
                a = fmaxf(a, __shfl_xor(a, 4)); a = fmaxf(a, __shfl_xor(a, 8));
                float mn0 = fmaxf(m0[i], a);
                cf0[i] = exp2a(m0[i] - mn0); m0[i] = mn0; ls0[i] *= cf0[i];
                float b = tl1[i];
                b = fmaxf(b, __shfl_xor(b, 1)); b = fmaxf(b, __shfl_xor(b, 2));
                b = fmaxf(b, __shfl_xor(b, 4)); b = fmaxf(b, __shfl_xor(b, 8));
                float mn1 = fmaxf(m1[i], b);
                cf1[i] = exp2a(m1[i] - mn1); m1[i] = mn1; ls1[i] *= cf1[i];
            }
            #pragma unroll
            for (int f = 0; f < 8; ++f) { o0[f] *= cf0; o1[f] *= cf1; }
        }
        #pragma unroll
        for (int tt = 0; tt < 4; ++tt)
            #pragma unroll
            for (int i = 0; i < 4; ++i) {
                int r0 = lg*4 + i;
                float p0 = exp2a(s0[tt][i] - m0[i]);
                ls0[i] += p0;
                *(f16*)(Pw + ((r0*128 + (tt*16+lr)*2) ^ ((r0 & 7) << 4))) = (f16)p0;
                int r1 = 16 + r0;
                float p1 = exp2a(s1[tt][i] - m1[i]);
                ls1[i] += p1;
                *(f16*)(Pw + ((r1*128 + (tt*16+lr)*2) ^ ((r1 & 7) << 4))) = (f16)p1;
            }
        asm volatile("s_waitcnt lgkmcnt(0)" ::: "memory");
        __builtin_amdgcn_sched_barrier(0);

        __builtin_amdgcn_s_setprio(1);
        #pragma unroll
        for (int kw = 0; kw < 2; ++kw) {
            f16x8 pa0 = *(const f16x8*)(Pw + ((lr*128 + kw*64 + lg*16) ^ psw));
            f16x8 pa1 = *(const f16x8*)(Pw + (((16+lr)*128 + kw*64 + lg*16) ^ psw));
            #pragma unroll
            for (int f = 0; f < 8; ++f) {
                f16x8 vb = ld8((const f16*)(Vc + (f*16 + lr)*128 + voff[kw]));
                o0[f] = MFMA16(pa0, vb, o0[f]);
                o1[f] = MFMA16(pa1, vb, o1[f]);
            }
        }
        __builtin_amdgcn_s_setprio(0);
        asm volatile("s_waitcnt vmcnt(0)" ::: "memory");
        __syncthreads();
    }

    #pragma unroll
    for (int i = 0; i < 4; ++i) {
        float a = ls0[i];
        a += __shfl_xor(a, 1); a += __shfl_xor(a, 2); a += __shfl_xor(a, 4); a += __shfl_xor(a, 8);
        float inv0 = 1.0f / a;
        float b = ls1[i];
        b += __shfl_xor(b, 1); b += __shfl_xor(b, 2); b += __shfl_xor(b, 4); b += __shfl_xor(b, 8);
        float inv1 = 1.0f / b;
        #pragma unroll
        for (int f = 0; f < 8; ++f) {
            out16[(size_t)(q0 + lg*4 + i) * 2048 + h*128 + f*16 + lr]      = (f16)(o0[f][i] * inv0);
            out16[(size_t)(q0 + 16 + lg*4 + i) * 2048 + h*128 + f*16 + lr] = (f16)(o1[f][i] * inv1);
        }
    }
    #undef STAGE
}

extern "C" void kernel_launch(void* const* d_in, const int* in_sizes, int n_in,
                              void* d_out, int out_size, void* d_ws, size_t ws_size,
                              hipStream_t stream) {
    const float* h     = (const float*)d_in[0];
    const float* wq    = (const float*)d_in[1];
    const float* wk    = (const float*)d_in[2];
    const float* wv    = (const float*)d_in[3];
    const float* wo    = (const float*)d_in[4];
    const float* qnw   = (const float*)d_in[5];
    const float* knw   = (const float*)d_in[6];
    const float* sw1   = (const float*)d_in[7];
    const float* sb1   = (const float*)d_in[8];
    const float* sw2   = (const float*)d_in[9];
    const float* sb2   = (const float*)d_in[10];
    const float* sscal = (const float*)d_in[11];
    const float* ka    = (const float*)d_in[12];
    const float* kb    = (const float*)d_in[13];
    const float* cosb  = (const float*)d_in[14];
    const float* sinb  = (const float*)d_in[15];
    float* outp = (float*)d_out;

    char* ws = (char*)d_ws;
    size_t off = 0;
    f16*    h16    = (f16*)(ws + off);   off += (size_t)4096*2048*2;
    f16*    wqkvt  = (f16*)(ws + off);   off += (size_t)3072*2048*2;
    f16*    wot    = (f16*)(ws + off);   off += (size_t)2048*2048*2;
    float*  qkvraw = (float*)(ws + off); off += (size_t)4096*3072*4;
    f16*    qr     = (f16*)(ws + off);   off += (size_t)4096*2048*2;
    float*  kn     = (float*)(ws + off); off += (size_t)4096*512*4;
    f16*    attn16 = (f16*)(ws + off);   off += (size_t)4096*2048*2;
    float*  T      = (float*)(ws + off); off += (size_t)2*32*16*512*4;
    f16*    Kf     = (f16*)(ws + off);   off += (size_t)4*2688*128*2;
    f16*    VfT    = (f16*)(ws + off);   off += (size_t)4*128*2688*2;
    double* logitsD= (double*)(ws + off);off += (size_t)4096*8;
    float*  iw     = (float*)(ws + off); off += (size_t)4096*4;
    int*    sel    = (int*)(ws + off);   off += (size_t)2048*4;

    k_mlp<<<1024, 256, 0, stream>>>(h, sw1, sb1, sw2, sb2, logitsD, iw, h16);
    k_transpose_qkv<<<dim3(96,64), dim3(32,8), 0, stream>>>(wq, wk, wv, wqkvt);
    k_transpose<<<dim3(64,64), dim3(32,8), 0, stream>>>(wo, wot, 2048, 0);
    k_topk<<<1, 1024, 0, stream>>>(logitsD, sel);
    k_gemm<<<dim3(24,32), 256, 0, stream>>>(h16, wqkvt, qkvraw, 4096, 3072, 2048);
    k_norm<<<4096, 320, 0, stream>>>(qkvraw, qnw, knw, cosb, sinb, qr, kn);
    k_gather<<<2048, 128, 0, stream>>>(sel, kn, qkvraw, cosb, sinb, Kf, VfT);
    k_sketch1<<<dim3(512,2), 256, 0, stream>>>(kn, qkvraw, iw, kb, T);
    k_sketch2<<<dim3(640,2), 256, 0, stream>>>(T, ka, sscal, Kf, VfT);
    k_attn<<<dim3(32,16), 256, 0, stream>>>(qr, Kf, VfT, attn16);
    k_gemm<<<dim3(16,32), 256, 0, stream>>>(attn16, wot, outp, 4096, 2048, 2048);
}